// Round 5
// baseline (590.461 us; speedup 1.0000x reference)
//
#include <hip/hip_runtime.h>
#include <math.h>

// MambaBlock: B=4, L=1024, D_MODEL=512, D_INNER=1024, D_STATE=16, D_CONV=4, DT_RANK=32
// All inputs/outputs are float32.
// Activation layout this round: time-contiguous (transposed) for everything the
// scan touches: xzT[2048][4096], uT[1024][4096], deltaT[1024][4096], yT[1024][4096].
#define B_   4
#define L_   1024
#define DM   512
#define DI   1024
#define NS   16
#define XDC  64      // DT_RANK + 2*D_STATE
#define BL   4096    // B_*L_

// C[M,N] = A * W^T, fp32.  A is [M,K] (atrans=0, row stride lda) or
// transposed [K,M] (atrans=1, row stride lda = M-stride). W is [N,K] row stride ldw.
// 128x64 tile, 8x4 per thread, float4 global loads.
// epi: 0 none; 1 softplus(v+bias[n]); 2 v+resid[m*N+n]; 3 softplus(v+bias[m])
__global__ __launch_bounds__(256) void gemm_tn(const float* __restrict__ A,
        const float* __restrict__ W, float* __restrict__ C,
        int M, int N, int K, int lda, int ldw, int ldc, int atrans,
        int epi, const float* __restrict__ bias, const float* __restrict__ resid)
{
    __shared__ float As[16][132];   // [k][m]
    __shared__ float Ws[16][68];    // [k][n]
    const int tid = threadIdx.x;
    const int tx = tid & 15, ty = tid >> 4;
    const int n0 = blockIdx.x * 64, m0 = blockIdx.y * 128;
    float acc[8][4] = {};

    for (int k0 = 0; k0 < K; k0 += 16) {
        if (atrans) {
            // AT[k][m]: 16 k-rows x 128 m = 512 float4, 2 per thread
            #pragma unroll
            for (int i = 0; i < 2; i++) {
                int idx = tid * 2 + i;          // 0..511
                int k = idx >> 5, m4 = (idx & 31) * 4;
                const float4 v = *(const float4*)&A[(size_t)(k0 + k) * lda + m0 + m4];
                As[k][m4 + 0] = v.x; As[k][m4 + 1] = v.y;
                As[k][m4 + 2] = v.z; As[k][m4 + 3] = v.w;
            }
        } else {
            // A[m][k]: 128 rows x 16 cols = 512 float4, 2 per thread
            #pragma unroll
            for (int i = 0; i < 2; i++) {
                int idx = tid * 2 + i;
                int r = idx >> 2, c4 = (idx & 3) * 4;
                const float4 v = *(const float4*)&A[(size_t)(m0 + r) * lda + k0 + c4];
                As[c4 + 0][r] = v.x; As[c4 + 1][r] = v.y;
                As[c4 + 2][r] = v.z; As[c4 + 3][r] = v.w;
            }
        }
        // W tile: 64 rows x 16 cols = 256 float4, 1 per thread
        {
            int r = tid >> 2, c4 = (tid & 3) * 4;
            const float4 v = *(const float4*)&W[(size_t)(n0 + r) * ldw + k0 + c4];
            Ws[c4 + 0][r] = v.x; Ws[c4 + 1][r] = v.y;
            Ws[c4 + 2][r] = v.z; Ws[c4 + 3][r] = v.w;
        }
        __syncthreads();
        #pragma unroll
        for (int kk = 0; kk < 16; kk++) {
            float a[8], b[4];
            #pragma unroll
            for (int i = 0; i < 8; i++) a[i] = As[kk][ty * 8 + i];
            #pragma unroll
            for (int j = 0; j < 4; j++) b[j] = Ws[kk][tx * 4 + j];
            #pragma unroll
            for (int i = 0; i < 8; i++)
                #pragma unroll
                for (int j = 0; j < 4; j++)
                    acc[i][j] = fmaf(a[i], b[j], acc[i][j]);
        }
        __syncthreads();
    }

    #pragma unroll
    for (int i = 0; i < 8; i++) {
        int m = m0 + ty * 8 + i;
        int nb = n0 + tx * 4;
        float4 v = make_float4(acc[i][0], acc[i][1], acc[i][2], acc[i][3]);
        if (epi == 1) {
            v.x += bias[nb + 0]; v.y += bias[nb + 1];
            v.z += bias[nb + 2]; v.w += bias[nb + 3];
            v.x = (v.x > 20.f) ? v.x : log1pf(__expf(v.x));
            v.y = (v.y > 20.f) ? v.y : log1pf(__expf(v.y));
            v.z = (v.z > 20.f) ? v.z : log1pf(__expf(v.z));
            v.w = (v.w > 20.f) ? v.w : log1pf(__expf(v.w));
        } else if (epi == 2) {
            const float4 rv = *(const float4*)&resid[(size_t)m * N + nb];
            v.x += rv.x; v.y += rv.y; v.z += rv.z; v.w += rv.w;
        } else if (epi == 3) {
            float bm = bias[m];
            v.x += bm; v.y += bm; v.z += bm; v.w += bm;
            v.x = (v.x > 20.f) ? v.x : log1pf(__expf(v.x));
            v.y = (v.y > 20.f) ? v.y : log1pf(__expf(v.y));
            v.z = (v.z > 20.f) ? v.z : log1pf(__expf(v.z));
            v.w = (v.w > 20.f) ? v.w : log1pf(__expf(v.w));
        }
        *(float4*)&C[(size_t)m * ldc + nb] = v;
    }
}

// depthwise causal conv (k=4) + bias + SiLU, channel-major layout.
// reads xzT[d][bl] (rows 0..1023 = xs), writes uT[d][bl]. Both coalesced.
__global__ __launch_bounds__(256) void conv_silu(const float* __restrict__ xzT,
        const float* __restrict__ cw, const float* __restrict__ cb,
        float* __restrict__ uT)
{
    int idx = blockIdx.x * 256 + threadIdx.x;   // d*4096 + bl
    int d  = idx >> 12;
    int bl = idx & 4095;
    int l  = bl & (L_ - 1);
    const float* row = xzT + (size_t)d * BL;
    float acc = cb[d];
    #pragma unroll
    for (int k = 0; k < 4; k++) {
        int ls = l - 3 + k;
        if (ls >= 0)
            acc = fmaf(row[bl - 3 + k], cw[d * 4 + k], acc);
    }
    uT[idx] = acc / (1.f + __expf(-acc));        // SiLU
}

// selective scan, time-contiguous layout: one lane per (b, d, n), 16-step chunks.
// delta/u loads: 4 float4 each (redundant across the 16-lane group -> L1 broadcast).
// B/C: imm-offset scalar loads (stride 256 B). exp/dBu hoisted; serial chain is
// 16 fmafs. Butterfly reduce at chunk end; lane 0 gates and stores 4 float4.
__global__ __launch_bounds__(256) void scan_kernel(const float* __restrict__ deltaT,
        const float* __restrict__ uT, const float* __restrict__ xdbl,
        const float* __restrict__ xzT, const float* __restrict__ A_log,
        const float* __restrict__ Dp, float* __restrict__ yT)
{
    const int t = blockIdx.x * 256 + threadIdx.x;
    const int n = t & 15;
    const int g = t >> 4;             // (b,d) group
    const int d = g & (DI - 1);
    const int b = g >> 10;

    const float Acoef = -__expf(A_log[d * NS + n]);
    const float Dd = Dp[d];
    float h = 0.f;

    const size_t base_t = (size_t)d * BL + b * L_;          // deltaT/uT/yT
    const size_t base_z = (size_t)(DI + d) * BL + b * L_;   // z inside xzT
    const size_t base_x = (size_t)b * L_ * XDC;             // xdbl

    for (int l0 = 0; l0 < L_; l0 += 16) {
        float dv[16], uv[16];
        {
            const float4* dp = (const float4*)(deltaT + base_t + l0);
            const float4* up = (const float4*)(uT + base_t + l0);
            #pragma unroll
            for (int i = 0; i < 4; i++) {
                *(float4*)&dv[i * 4] = dp[i];
                *(float4*)&uv[i * 4] = up[i];
            }
        }
        float Bv[16], Cv[16];
        {
            const float* xp = xdbl + base_x + (size_t)l0 * XDC + 32 + n;
            #pragma unroll
            for (int j = 0; j < 16; j++) {
                Bv[j] = xp[j * XDC];
                Cv[j] = xp[j * XDC + 16];
            }
        }

        // hoist off the recurrence: Bv <- dBu, dv <- dA
        #pragma unroll
        for (int j = 0; j < 16; j++) {
            Bv[j] *= dv[j] * uv[j];
            dv[j] = __expf(dv[j] * Acoef);
        }

        // serial recurrence
        float p[16];
        #pragma unroll
        for (int j = 0; j < 16; j++) {
            h = fmaf(dv[j], h, Bv[j]);
            p[j] = h * Cv[j];
        }

        // batched butterfly reductions (16 independent trees per level)
        #pragma unroll
        for (int m = 1; m <= 8; m <<= 1) {
            #pragma unroll
            for (int j = 0; j < 16; j++)
                p[j] += __shfl_xor(p[j], m);
        }

        if (n == 0) {
            float zv[16];
            const float4* zp = (const float4*)(xzT + base_z + l0);
            #pragma unroll
            for (int i = 0; i < 4; i++) *(float4*)&zv[i * 4] = zp[i];
            float yv[16];
            #pragma unroll
            for (int j = 0; j < 16; j++) {
                float v = p[j] + uv[j] * Dd;
                yv[j] = v * zv[j] / (1.f + __expf(-zv[j]));   // * silu(z)
            }
            float4* yp = (float4*)(yT + base_t + l0);
            #pragma unroll
            for (int i = 0; i < 4; i++) yp[i] = *(float4*)&yv[i * 4];
        }
    }
}

// LayerNorm over last dim (512), one block per row, fp32 out.
__global__ __launch_bounds__(256) void ln_kernel(const float* __restrict__ r,
        const float* __restrict__ lnw, const float* __restrict__ lnb,
        float* __restrict__ out)
{
    int row = blockIdx.x;
    const float* rr = r + (size_t)row * DM;
    float v0 = rr[threadIdx.x], v1 = rr[threadIdx.x + 256];
    float s = v0 + v1, s2 = v0 * v0 + v1 * v1;
    #pragma unroll
    for (int off = 32; off > 0; off >>= 1) {
        s  += __shfl_down(s, off);
        s2 += __shfl_down(s2, off);
    }
    __shared__ float ls[4], ls2[4];
    __shared__ float mu_s, rstd_s;
    int wid = threadIdx.x >> 6, lane = threadIdx.x & 63;
    if (lane == 0) { ls[wid] = s; ls2[wid] = s2; }
    __syncthreads();
    if (threadIdx.x == 0) {
        float S = ls[0] + ls[1] + ls[2] + ls[3];
        float S2 = ls2[0] + ls2[1] + ls2[2] + ls2[3];
        float mu = S * (1.f / DM);
        float var = S2 * (1.f / DM) - mu * mu;
        mu_s = mu;
        rstd_s = rsqrtf(var + 1e-5f);
    }
    __syncthreads();
    float mu = mu_s, rstd = rstd_s;
    out[(size_t)row * DM + threadIdx.x] =
        (v0 - mu) * rstd * lnw[threadIdx.x] + lnb[threadIdx.x];
    out[(size_t)row * DM + threadIdx.x + 256] =
        (v1 - mu) * rstd * lnw[threadIdx.x + 256] + lnb[threadIdx.x + 256];
}

extern "C" void kernel_launch(void* const* d_in, const int* in_sizes, int n_in,
                              void* d_out, int out_size, void* d_ws, size_t ws_size,
                              hipStream_t stream)
{
    const float* x         = (const float*)d_in[0];
    const float* in_proj_w = (const float*)d_in[1];
    const float* conv_w    = (const float*)d_in[2];
    const float* conv_b    = (const float*)d_in[3];
    const float* x_proj_w  = (const float*)d_in[4];
    const float* dt_proj_w = (const float*)d_in[5];
    const float* dt_proj_b = (const float*)d_in[6];
    const float* A_log     = (const float*)d_in[7];
    const float* Dvec      = (const float*)d_in[8];
    const float* out_proj_w= (const float*)d_in[9];
    const float* ln_w      = (const float*)d_in[10];
    const float* ln_b      = (const float*)d_in[11];
    float* out = (float*)d_out;

    float* ws     = (float*)d_ws;
    float* xzT    = ws;                                  // 2048 x 4096
    float* uT     = xzT    + (size_t)2048 * BL;          // 1024 x 4096
    float* xdbl   = uT     + (size_t)DI * BL;            // 4096 x 64
    float* deltaT = xdbl   + (size_t)BL * XDC;           // 1024 x 4096
    float* yT     = deltaT + (size_t)DI * BL;            // 1024 x 4096
    float* r      = yT     + (size_t)DI * BL;            // 4096 x 512

    dim3 blk(256);

    // 1) xzT = (x @ in_proj_w^T)^T : M=2048(e), N=4096(bl), K=512
    //    A = in_proj_w [2048x512], W = x [4096x512]
    gemm_tn<<<dim3(BL / 64, 2048 / 128), blk, 0, stream>>>(
        in_proj_w, x, xzT, 2048, BL, DM, DM, DM, BL, 0, 0, nullptr, nullptr);

    // 2) uT = silu(causal_conv(xsT) + cb)   (channel-major both sides)
    conv_silu<<<(DI * BL) / 256, blk, 0, stream>>>(xzT, conv_w, conv_b, uT);

    // 3) xdbl = u @ x_proj_w^T : M=4096, N=64, K=1024, A = uT (transposed layout)
    gemm_tn<<<dim3(1, BL / 128), blk, 0, stream>>>(
        uT, x_proj_w, xdbl, BL, XDC, DI, BL, DI, XDC, 1, 0, nullptr, nullptr);

    // 4) deltaT = softplus(dt_proj_w @ dt^T + b) : M=1024(d), N=4096(bl), K=32
    //    A = dt_proj_w [1024x32], W = xdbl (first 32 cols, ldw=64), bias per row
    gemm_tn<<<dim3(BL / 64, DI / 128), blk, 0, stream>>>(
        dt_proj_w, xdbl, deltaT, DI, BL, 32, 32, XDC, BL, 0, 3, dt_proj_b, nullptr);

    // 5) selective scan + gate  (time-contiguous I/O)
    scan_kernel<<<(BL * NS) / 256, blk, 0, stream>>>(
        deltaT, uT, xdbl, xzT, A_log, Dvec, yT);

    // 6) r = y @ out_proj_w^T + x : M=4096, N=512, K=1024, A = yT (transposed)
    gemm_tn<<<dim3(DM / 64, BL / 128), blk, 0, stream>>>(
        yT, out_proj_w, r, BL, DM, DI, BL, DI, DM, 1, 2, nullptr, x);

    // 7) LayerNorm -> fp32 out
    ln_kernel<<<BL, blk, 0, stream>>>(r, ln_w, ln_b, out);
}

// Round 6
// 348.196 us; speedup vs baseline: 1.6958x; 1.6958x over previous
//
#include <hip/hip_runtime.h>
#include <hip/hip_bf16.h>
#include <math.h>

// MambaBlock: B=4, L=1024, D_MODEL=512, D_INNER=1024, D_STATE=16, D_CONV=4, DT_RANK=32
// fp32 in/out. bf16 MFMA for the two big GEMMs; fp32 SIMT for the small ones.
#define B_   4
#define L_   1024
#define DM   512
#define DI   1024
#define NS   16
#define XDC  64      // DT_RANK + 2*D_STATE
#define BL   4096    // B_*L_

typedef short bfrag __attribute__((ext_vector_type(8)));   // 8 bf16
typedef float ffrag __attribute__((ext_vector_type(4)));   // 4 fp32 acc

__device__ __forceinline__ ushort f2bf(float v) {
    __hip_bfloat16 h = __float2bfloat16(v);
    return *(ushort*)&h;
}

// fp32 -> bf16 cast, 4 elems/thread
__global__ __launch_bounds__(256) void cast_bf16(const float* __restrict__ in,
        ushort* __restrict__ out, int n4)
{
    int i = blockIdx.x * 256 + threadIdx.x;
    if (i >= n4) return;
    float4 v = ((const float4*)in)[i];
    ushort4 o;
    o.x = f2bf(v.x); o.y = f2bf(v.y); o.z = f2bf(v.z); o.w = f2bf(v.w);
    ((ushort4*)out)[i] = o;
}

// MFMA bf16 TN GEMM: C[M,N] = A[M,K] * B[N,K]^T, fp32 out.
// 128x128 block tile, BK=32, 4 waves (2x2), wave tile 64x64 (4x4 of 16x16x32).
// EPI: 0 none; 2 C += resid[m*ldc+n]
template<int EPI>
__global__ __launch_bounds__(256) void gemm_mfma(const ushort* __restrict__ A,
        const ushort* __restrict__ B, float* __restrict__ C,
        int K, int ldc, const float* __restrict__ resid)
{
    __shared__ ushort As[128][40];   // pad 32->40 bf16 (80 B rows, 16B-aligned)
    __shared__ ushort Bs[128][40];
    const int tid = threadIdx.x;
    const int lane = tid & 63, wave = tid >> 6;
    const int wm = (wave & 1) * 64, wn = (wave >> 1) * 64;
    const int l15 = lane & 15, quad = lane >> 4;
    const int m0 = blockIdx.y * 128, n0 = blockIdx.x * 128;

    ffrag acc[4][4] = {};

    for (int k0 = 0; k0 < K; k0 += 32) {
        #pragma unroll
        for (int i = 0; i < 2; i++) {
            int chunk = tid + i * 256;              // 0..511
            int row = chunk >> 2, kk8 = (chunk & 3) * 8;
            *(uint4*)&As[row][kk8] = *(const uint4*)&A[(size_t)(m0 + row) * K + k0 + kk8];
            *(uint4*)&Bs[row][kk8] = *(const uint4*)&B[(size_t)(n0 + row) * K + k0 + kk8];
        }
        __syncthreads();
        bfrag af[4], bfv[4];
        #pragma unroll
        for (int i = 0; i < 4; i++) {
            af[i]  = *(const bfrag*)&As[wm + i * 16 + l15][quad * 8];
            bfv[i] = *(const bfrag*)&Bs[wn + i * 16 + l15][quad * 8];
        }
        #pragma unroll
        for (int i = 0; i < 4; i++)
            #pragma unroll
            for (int j = 0; j < 4; j++)
                acc[i][j] = __builtin_amdgcn_mfma_f32_16x16x32_bf16(af[i], bfv[j], acc[i][j], 0, 0, 0);
        __syncthreads();
    }

    // C/D layout: row = quad*4 + reg, col = lane&15
    #pragma unroll
    for (int i = 0; i < 4; i++) {
        #pragma unroll
        for (int j = 0; j < 4; j++) {
            int n = n0 + wn + j * 16 + l15;
            #pragma unroll
            for (int r = 0; r < 4; r++) {
                int m = m0 + wm + i * 16 + quad * 4 + r;
                float v = acc[i][j][r];
                if (EPI == 2) v += resid[(size_t)m * ldc + n];
                C[(size_t)m * ldc + n] = v;
            }
        }
    }
}

// SIMT fp32 GEMM: C[M,N] = A * W^T. MT x 64 tile, (MT/16) x 4 per thread.
// A: [M,K] (atrans=0, stride lda) or [K,M] (atrans=1, stride lda).
// epi: 0 none; 3 softplus(v + bias[m])
template<int MT>
__global__ __launch_bounds__(256) void gemm_tn(const float* __restrict__ A,
        const float* __restrict__ W, float* __restrict__ C,
        int N, int K, int lda, int ldw, int ldc, int atrans,
        int epi, const float* __restrict__ bias)
{
    __shared__ float As[16][MT + 4];
    __shared__ float Ws[16][68];
    const int tid = threadIdx.x;
    const int tx = tid & 15, ty = tid >> 4;
    const int n0 = blockIdx.x * 64, m0 = blockIdx.y * MT;
    const int RM = MT / 16;
    float acc[RM][4] = {};

    for (int k0 = 0; k0 < K; k0 += 16) {
        const int nchunk = MT * 4;                  // float4s in A tile
        if (atrans) {
            #pragma unroll
            for (int i = 0; i < (nchunk + 255) / 256; i++) {
                int idx = tid + i * 256;
                if (nchunk < 256 * (i + 1) && idx >= nchunk) break;
                int k = idx / (MT / 4), m4 = (idx % (MT / 4)) * 4;
                const float4 v = *(const float4*)&A[(size_t)(k0 + k) * lda + m0 + m4];
                As[k][m4 + 0] = v.x; As[k][m4 + 1] = v.y;
                As[k][m4 + 2] = v.z; As[k][m4 + 3] = v.w;
            }
        } else {
            #pragma unroll
            for (int i = 0; i < (nchunk + 255) / 256; i++) {
                int idx = tid + i * 256;
                if (nchunk < 256 * (i + 1) && idx >= nchunk) break;
                int r = idx >> 2, c4 = (idx & 3) * 4;
                const float4 v = *(const float4*)&A[(size_t)(m0 + r) * lda + k0 + c4];
                As[c4 + 0][r] = v.x; As[c4 + 1][r] = v.y;
                As[c4 + 2][r] = v.z; As[c4 + 3][r] = v.w;
            }
        }
        {
            int r = tid >> 2, c4 = (tid & 3) * 4;
            const float4 v = *(const float4*)&W[(size_t)(n0 + r) * ldw + k0 + c4];
            Ws[c4 + 0][r] = v.x; Ws[c4 + 1][r] = v.y;
            Ws[c4 + 2][r] = v.z; Ws[c4 + 3][r] = v.w;
        }
        __syncthreads();
        #pragma unroll
        for (int kk = 0; kk < 16; kk++) {
            float a[RM], b[4];
            #pragma unroll
            for (int i = 0; i < RM; i++) a[i] = As[kk][ty * RM + i];
            #pragma unroll
            for (int j = 0; j < 4; j++) b[j] = Ws[kk][tx * 4 + j];
            #pragma unroll
            for (int i = 0; i < RM; i++)
                #pragma unroll
                for (int j = 0; j < 4; j++)
                    acc[i][j] = fmaf(a[i], b[j], acc[i][j]);
        }
        __syncthreads();
    }

    #pragma unroll
    for (int i = 0; i < RM; i++) {
        int m = m0 + ty * RM + i;
        int nb = n0 + tx * 4;
        float4 v = make_float4(acc[i][0], acc[i][1], acc[i][2], acc[i][3]);
        if (epi == 3) {
            float bm = bias[m];
            v.x += bm; v.y += bm; v.z += bm; v.w += bm;
            v.x = (v.x > 20.f) ? v.x : log1pf(__expf(v.x));
            v.y = (v.y > 20.f) ? v.y : log1pf(__expf(v.y));
            v.z = (v.z > 20.f) ? v.z : log1pf(__expf(v.z));
            v.w = (v.w > 20.f) ? v.w : log1pf(__expf(v.w));
        }
        *(float4*)&C[(size_t)m * ldc + nb] = v;
    }
}

// depthwise causal conv (k=4) + bias + SiLU, channel-major.
__global__ __launch_bounds__(256) void conv_silu(const float* __restrict__ xzT,
        const float* __restrict__ cw, const float* __restrict__ cb,
        float* __restrict__ uT)
{
    int idx = blockIdx.x * 256 + threadIdx.x;   // d*4096 + bl
    int d  = idx >> 12;
    int bl = idx & 4095;
    int l  = bl & (L_ - 1);
    const float* row = xzT + (size_t)d * BL;
    float acc = cb[d];
    #pragma unroll
    for (int k = 0; k < 4; k++) {
        int ls = l - 3 + k;
        if (ls >= 0)
            acc = fmaf(row[bl - 3 + k], cw[d * 4 + k], acc);
    }
    uT[idx] = acc / (1.f + __expf(-acc));        // SiLU
}

// selective scan, time-contiguous: one lane per (b, d, n), 16-step chunks.
__global__ __launch_bounds__(256) void scan_kernel(const float* __restrict__ deltaT,
        const float* __restrict__ uT, const float* __restrict__ xdbl,
        const float* __restrict__ xzT, const float* __restrict__ A_log,
        const float* __restrict__ Dp, float* __restrict__ yT)
{
    const int t = blockIdx.x * 256 + threadIdx.x;
    const int n = t & 15;
    const int g = t >> 4;
    const int d = g & (DI - 1);
    const int b = g >> 10;

    const float Acoef = -__expf(A_log[d * NS + n]);
    const float Dd = Dp[d];
    float h = 0.f;

    const size_t base_t = (size_t)d * BL + b * L_;
    const size_t base_z = (size_t)(DI + d) * BL + b * L_;
    const size_t base_x = (size_t)b * L_ * XDC;

    for (int l0 = 0; l0 < L_; l0 += 16) {
        float dv[16], uv[16];
        {
            const float4* dp = (const float4*)(deltaT + base_t + l0);
            const float4* up = (const float4*)(uT + base_t + l0);
            #pragma unroll
            for (int i = 0; i < 4; i++) {
                *(float4*)&dv[i * 4] = dp[i];
                *(float4*)&uv[i * 4] = up[i];
            }
        }
        float Bv[16], Cv[16];
        {
            const float* xp = xdbl + base_x + (size_t)l0 * XDC + 32 + n;
            #pragma unroll
            for (int j = 0; j < 16; j++) {
                Bv[j] = xp[j * XDC];
                Cv[j] = xp[j * XDC + 16];
            }
        }
        #pragma unroll
        for (int j = 0; j < 16; j++) {
            Bv[j] *= dv[j] * uv[j];
            dv[j] = __expf(dv[j] * Acoef);
        }
        float p[16];
        #pragma unroll
        for (int j = 0; j < 16; j++) {
            h = fmaf(dv[j], h, Bv[j]);
            p[j] = h * Cv[j];
        }
        #pragma unroll
        for (int m = 1; m <= 8; m <<= 1) {
            #pragma unroll
            for (int j = 0; j < 16; j++)
                p[j] += __shfl_xor(p[j], m);
        }
        if (n == 0) {
            float zv[16];
            const float4* zp = (const float4*)(xzT + base_z + l0);
            #pragma unroll
            for (int i = 0; i < 4; i++) *(float4*)&zv[i * 4] = zp[i];
            float yv[16];
            #pragma unroll
            for (int j = 0; j < 16; j++) {
                float v = p[j] + uv[j] * Dd;
                yv[j] = v * zv[j] / (1.f + __expf(-zv[j]));
            }
            float4* yp = (float4*)(yT + base_t + l0);
            #pragma unroll
            for (int i = 0; i < 4; i++) yp[i] = *(float4*)&yv[i * 4];
        }
    }
}

// yT fp32 [DI][BL] -> yB bf16 [BL][DI], 64x64 LDS tiles.
__global__ __launch_bounds__(256) void transpose_cast(const float* __restrict__ yT,
        ushort* __restrict__ yB)
{
    __shared__ float t[64][65];
    const int bl0 = blockIdx.x * 64, d0 = blockIdx.y * 64;
    const int tid = threadIdx.x;
    #pragma unroll
    for (int i = 0; i < 4; i++) {
        int chunk = tid + i * 256;          // 0..1023
        int dr = chunk >> 4, c4 = (chunk & 15) * 4;
        const float4 v = *(const float4*)&yT[(size_t)(d0 + dr) * BL + bl0 + c4];
        t[dr][c4 + 0] = v.x; t[dr][c4 + 1] = v.y;
        t[dr][c4 + 2] = v.z; t[dr][c4 + 3] = v.w;
    }
    __syncthreads();
    #pragma unroll
    for (int i = 0; i < 4; i++) {
        int chunk = tid + i * 256;
        int br = chunk >> 4, dc4 = (chunk & 15) * 4;
        ushort4 o;
        o.x = f2bf(t[dc4 + 0][br]); o.y = f2bf(t[dc4 + 1][br]);
        o.z = f2bf(t[dc4 + 2][br]); o.w = f2bf(t[dc4 + 3][br]);
        *(ushort4*)&yB[(size_t)(bl0 + br) * DI + d0 + dc4] = o;
    }
}

// LayerNorm over last dim (512), one block per row, fp32 out.
__global__ __launch_bounds__(256) void ln_kernel(const float* __restrict__ r,
        const float* __restrict__ lnw, const float* __restrict__ lnb,
        float* __restrict__ out)
{
    int row = blockIdx.x;
    const float* rr = r + (size_t)row * DM;
    float v0 = rr[threadIdx.x], v1 = rr[threadIdx.x + 256];
    float s = v0 + v1, s2 = v0 * v0 + v1 * v1;
    #pragma unroll
    for (int off = 32; off > 0; off >>= 1) {
        s  += __shfl_down(s, off);
        s2 += __shfl_down(s2, off);
    }
    __shared__ float ls[4], ls2[4];
    __shared__ float mu_s, rstd_s;
    int wid = threadIdx.x >> 6, lane = threadIdx.x & 63;
    if (lane == 0) { ls[wid] = s; ls2[wid] = s2; }
    __syncthreads();
    if (threadIdx.x == 0) {
        float S = ls[0] + ls[1] + ls[2] + ls[3];
        float S2 = ls2[0] + ls2[1] + ls2[2] + ls2[3];
        float mu = S * (1.f / DM);
        float var = S2 * (1.f / DM) - mu * mu;
        mu_s = mu;
        rstd_s = rsqrtf(var + 1e-5f);
    }
    __syncthreads();
    float mu = mu_s, rstd = rstd_s;
    out[(size_t)row * DM + threadIdx.x] =
        (v0 - mu) * rstd * lnw[threadIdx.x] + lnb[threadIdx.x];
    out[(size_t)row * DM + threadIdx.x + 256] =
        (v1 - mu) * rstd * lnw[threadIdx.x + 256] + lnb[threadIdx.x + 256];
}

extern "C" void kernel_launch(void* const* d_in, const int* in_sizes, int n_in,
                              void* d_out, int out_size, void* d_ws, size_t ws_size,
                              hipStream_t stream)
{
    const float* x         = (const float*)d_in[0];
    const float* in_proj_w = (const float*)d_in[1];
    const float* conv_w    = (const float*)d_in[2];
    const float* conv_b    = (const float*)d_in[3];
    const float* x_proj_w  = (const float*)d_in[4];
    const float* dt_proj_w = (const float*)d_in[5];
    const float* dt_proj_b = (const float*)d_in[6];
    const float* A_log     = (const float*)d_in[7];
    const float* Dvec      = (const float*)d_in[8];
    const float* out_proj_w= (const float*)d_in[9];
    const float* ln_w      = (const float*)d_in[10];
    const float* ln_b      = (const float*)d_in[11];
    float* out = (float*)d_out;

    // fp32 regions (floats)
    float* ws     = (float*)d_ws;
    float* xzT    = ws;                                  // 2048 x 4096 (32 MB)
    float* uT     = xzT    + (size_t)2048 * BL;          // 1024 x 4096 (16 MB)
    float* xdbl   = uT     + (size_t)DI * BL;            // 4096 x 64   (1 MB)
    float* deltaT = xdbl   + (size_t)BL * XDC;           // 1024 x 4096 (16 MB)
    float* yT     = deltaT + (size_t)DI * BL;            // 1024 x 4096 (16 MB)
    float* r      = yT     + (size_t)DI * BL;            // 4096 x 512  (8 MB)
    // bf16 aliases over time-dead fp32 regions:
    ushort* xB    = (ushort*)yT;                         // 4 MB, dead before scan writes yT
    ushort* yB    = (ushort*)deltaT;                     // 8 MB, deltaT dead after scan
    ushort* wOutB = (ushort*)deltaT + (size_t)4 * 1024 * 1024;   // +8 MB (cast after scan)
    ushort* wInB  = (ushort*)deltaT + (size_t)9 * 1024 * 1024 / 2; // +9 MB (dead after gemm1)

    dim3 blk(256);

    // 0) casts for gemm1
    cast_bf16<<<(BL * DM / 4 + 255) / 256, blk, 0, stream>>>(x, xB, BL * DM / 4);
    cast_bf16<<<(2048 * DM / 4 + 255) / 256, blk, 0, stream>>>(in_proj_w, wInB, 2048 * DM / 4);

    // 1) xzT[e][bl] = in_proj_w @ x^T : M=2048, N=4096, K=512 (MFMA)
    gemm_mfma<0><<<dim3(BL / 128, 2048 / 128), blk, 0, stream>>>(
        wInB, xB, xzT, DM, BL, nullptr);

    // 2) uT = silu(causal_conv(xsT) + cb)
    conv_silu<<<(DI * BL) / 256, blk, 0, stream>>>(xzT, conv_w, conv_b, uT);

    // 3) xdbl = u @ x_proj_w^T : M=4096 (MT=32 -> 128 blocks), N=64, K=1024
    gemm_tn<32><<<dim3(1, BL / 32), blk, 0, stream>>>(
        uT, x_proj_w, xdbl, XDC, DI, BL, DI, XDC, 1, 0, nullptr);

    // 4) deltaT = softplus(dt_proj_w @ dt^T + b[m]) : M=1024, N=4096, K=32
    gemm_tn<128><<<dim3(BL / 64, DI / 128), blk, 0, stream>>>(
        dt_proj_w, xdbl, deltaT, BL, 32, 32, XDC, BL, 0, 3, dt_proj_b);

    // 5) selective scan + gate
    scan_kernel<<<(BL * NS) / 256, blk, 0, stream>>>(
        deltaT, uT, xdbl, xzT, A_log, Dvec, yT);

    // 6a) yT -> yB (bf16, [bl][d]); cast out_proj_w
    transpose_cast<<<dim3(BL / 64, DI / 64), blk, 0, stream>>>(yT, yB);
    cast_bf16<<<(DM * DI / 4 + 255) / 256, blk, 0, stream>>>(out_proj_w, wOutB, DM * DI / 4);

    // 6b) r[bl][dm] = y @ out_proj_w^T + x : M=4096, N=512, K=1024 (MFMA, resid epi)
    gemm_mfma<2><<<dim3(DM / 128, BL / 128), blk, 0, stream>>>(
        yB, wOutB, r, DI, DM, x);

    // 7) LayerNorm -> fp32 out
    ln_kernel<<<BL, blk, 0, stream>>>(r, ln_w, ln_b, out);
}

// Round 7
// 321.356 us; speedup vs baseline: 1.8374x; 1.0835x over previous
//
#include <hip/hip_runtime.h>
#include <hip/hip_bf16.h>
#include <math.h>

// MambaBlock: B=4, L=1024, D_MODEL=512, D_INNER=1024, D_STATE=16, D_CONV=4, DT_RANK=32
// fp32 in/out. bf16 MFMA for the two big GEMMs; fp32 SIMT for the small ones.
// Scan: 3-pass chunk-decomposed (G=8 segments) for 8x wave parallelism.
#define B_   4
#define L_   1024
#define DM   512
#define DI   1024
#define NS   16
#define XDC  64      // DT_RANK + 2*D_STATE
#define BL   4096    // B_*L_
#define G_   8       // scan segments
#define SEG  128     // L_/G_

typedef short bfrag __attribute__((ext_vector_type(8)));   // 8 bf16
typedef float ffrag __attribute__((ext_vector_type(4)));   // 4 fp32 acc

__device__ __forceinline__ ushort f2bf(float v) {
    __hip_bfloat16 h = __float2bfloat16(v);
    return *(ushort*)&h;
}

// fp32 -> bf16 cast, 4 elems/thread
__global__ __launch_bounds__(256) void cast_bf16(const float* __restrict__ in,
        ushort* __restrict__ out, int n4)
{
    int i = blockIdx.x * 256 + threadIdx.x;
    if (i >= n4) return;
    float4 v = ((const float4*)in)[i];
    ushort4 o;
    o.x = f2bf(v.x); o.y = f2bf(v.y); o.z = f2bf(v.z); o.w = f2bf(v.w);
    ((ushort4*)out)[i] = o;
}

// MFMA bf16 TN GEMM: C[M,N] = A[M,K] * B[N,K]^T, fp32 out.
// 128x128 block tile, BK=32, 4 waves (2x2), wave tile 64x64 (4x4 of 16x16x32).
// EPI: 0 none; 2 C += resid[m*ldc+n]
template<int EPI>
__global__ __launch_bounds__(256) void gemm_mfma(const ushort* __restrict__ A,
        const ushort* __restrict__ B, float* __restrict__ C,
        int K, int ldc, const float* __restrict__ resid)
{
    __shared__ ushort As[128][40];
    __shared__ ushort Bs[128][40];
    const int tid = threadIdx.x;
    const int lane = tid & 63, wave = tid >> 6;
    const int wm = (wave & 1) * 64, wn = (wave >> 1) * 64;
    const int l15 = lane & 15, quad = lane >> 4;
    const int m0 = blockIdx.y * 128, n0 = blockIdx.x * 128;

    ffrag acc[4][4] = {};

    for (int k0 = 0; k0 < K; k0 += 32) {
        #pragma unroll
        for (int i = 0; i < 2; i++) {
            int chunk = tid + i * 256;
            int row = chunk >> 2, kk8 = (chunk & 3) * 8;
            *(uint4*)&As[row][kk8] = *(const uint4*)&A[(size_t)(m0 + row) * K + k0 + kk8];
            *(uint4*)&Bs[row][kk8] = *(const uint4*)&B[(size_t)(n0 + row) * K + k0 + kk8];
        }
        __syncthreads();
        bfrag af[4], bfv[4];
        #pragma unroll
        for (int i = 0; i < 4; i++) {
            af[i]  = *(const bfrag*)&As[wm + i * 16 + l15][quad * 8];
            bfv[i] = *(const bfrag*)&Bs[wn + i * 16 + l15][quad * 8];
        }
        #pragma unroll
        for (int i = 0; i < 4; i++)
            #pragma unroll
            for (int j = 0; j < 4; j++)
                acc[i][j] = __builtin_amdgcn_mfma_f32_16x16x32_bf16(af[i], bfv[j], acc[i][j], 0, 0, 0);
        __syncthreads();
    }

    #pragma unroll
    for (int i = 0; i < 4; i++) {
        #pragma unroll
        for (int j = 0; j < 4; j++) {
            int n = n0 + wn + j * 16 + l15;
            #pragma unroll
            for (int r = 0; r < 4; r++) {
                int m = m0 + wm + i * 16 + quad * 4 + r;
                float v = acc[i][j][r];
                if (EPI == 2) v += resid[(size_t)m * ldc + n];
                C[(size_t)m * ldc + n] = v;
            }
        }
    }
}

// SIMT fp32 GEMM: C[M,N] = A * W^T. MT x 64 tile.
// epi: 0 none; 3 softplus(v + bias[m])
template<int MT>
__global__ __launch_bounds__(256) void gemm_tn(const float* __restrict__ A,
        const float* __restrict__ W, float* __restrict__ C,
        int N, int K, int lda, int ldw, int ldc, int atrans,
        int epi, const float* __restrict__ bias)
{
    __shared__ float As[16][MT + 4];
    __shared__ float Ws[16][68];
    const int tid = threadIdx.x;
    const int tx = tid & 15, ty = tid >> 4;
    const int n0 = blockIdx.x * 64, m0 = blockIdx.y * MT;
    const int RM = MT / 16;
    float acc[RM][4] = {};

    for (int k0 = 0; k0 < K; k0 += 16) {
        const int nchunk = MT * 4;
        if (atrans) {
            #pragma unroll
            for (int i = 0; i < (nchunk + 255) / 256; i++) {
                int idx = tid + i * 256;
                if (nchunk < 256 * (i + 1) && idx >= nchunk) break;
                int k = idx / (MT / 4), m4 = (idx % (MT / 4)) * 4;
                const float4 v = *(const float4*)&A[(size_t)(k0 + k) * lda + m0 + m4];
                As[k][m4 + 0] = v.x; As[k][m4 + 1] = v.y;
                As[k][m4 + 2] = v.z; As[k][m4 + 3] = v.w;
            }
        } else {
            #pragma unroll
            for (int i = 0; i < (nchunk + 255) / 256; i++) {
                int idx = tid + i * 256;
                if (nchunk < 256 * (i + 1) && idx >= nchunk) break;
                int r = idx >> 2, c4 = (idx & 3) * 4;
                const float4 v = *(const float4*)&A[(size_t)(m0 + r) * lda + k0 + c4];
                As[c4 + 0][r] = v.x; As[c4 + 1][r] = v.y;
                As[c4 + 2][r] = v.z; As[c4 + 3][r] = v.w;
            }
        }
        {
            int r = tid >> 2, c4 = (tid & 3) * 4;
            const float4 v = *(const float4*)&W[(size_t)(n0 + r) * ldw + k0 + c4];
            Ws[c4 + 0][r] = v.x; Ws[c4 + 1][r] = v.y;
            Ws[c4 + 2][r] = v.z; Ws[c4 + 3][r] = v.w;
        }
        __syncthreads();
        #pragma unroll
        for (int kk = 0; kk < 16; kk++) {
            float a[RM], b[4];
            #pragma unroll
            for (int i = 0; i < RM; i++) a[i] = As[kk][ty * RM + i];
            #pragma unroll
            for (int j = 0; j < 4; j++) b[j] = Ws[kk][tx * 4 + j];
            #pragma unroll
            for (int i = 0; i < RM; i++)
                #pragma unroll
                for (int j = 0; j < 4; j++)
                    acc[i][j] = fmaf(a[i], b[j], acc[i][j]);
        }
        __syncthreads();
    }

    #pragma unroll
    for (int i = 0; i < RM; i++) {
        int m = m0 + ty * RM + i;
        int nb = n0 + tx * 4;
        float4 v = make_float4(acc[i][0], acc[i][1], acc[i][2], acc[i][3]);
        if (epi == 3) {
            float bm = bias[m];
            v.x += bm; v.y += bm; v.z += bm; v.w += bm;
            v.x = (v.x > 20.f) ? v.x : log1pf(__expf(v.x));
            v.y = (v.y > 20.f) ? v.y : log1pf(__expf(v.y));
            v.z = (v.z > 20.f) ? v.z : log1pf(__expf(v.z));
            v.w = (v.w > 20.f) ? v.w : log1pf(__expf(v.w));
        }
        *(float4*)&C[(size_t)m * ldc + nb] = v;
    }
}

// depthwise causal conv (k=4) + bias + SiLU, channel-major, 4 outputs/thread.
__global__ __launch_bounds__(256) void conv_silu(const float* __restrict__ xzT,
        const float* __restrict__ cw, const float* __restrict__ cb,
        float* __restrict__ uT)
{
    int i = blockIdx.x * 256 + threadIdx.x;     // over DI*BL/4
    int d  = i >> 10;
    int q  = i & 1023;
    int bl = q * 4;
    int l  = bl & (L_ - 1);
    const float* row = xzT + (size_t)d * BL;
    float4 cur = *(const float4*)&row[bl];
    float4 prev = make_float4(0.f, 0.f, 0.f, 0.f);
    if (l != 0) prev = *(const float4*)&row[bl - 4];
    float v[7] = { prev.y, prev.z, prev.w, cur.x, cur.y, cur.z, cur.w };
    float w0 = cw[d * 4 + 0], w1 = cw[d * 4 + 1], w2 = cw[d * 4 + 2], w3 = cw[d * 4 + 3];
    float bias = cb[d];
    float4 o;
    o.x = bias + w0 * v[0] + w1 * v[1] + w2 * v[2] + w3 * v[3];
    o.y = bias + w0 * v[1] + w1 * v[2] + w2 * v[3] + w3 * v[4];
    o.z = bias + w0 * v[2] + w1 * v[3] + w2 * v[4] + w3 * v[5];
    o.w = bias + w0 * v[3] + w1 * v[4] + w2 * v[5] + w3 * v[6];
    o.x = o.x / (1.f + __expf(-o.x));
    o.y = o.y / (1.f + __expf(-o.y));
    o.z = o.z / (1.f + __expf(-o.z));
    o.w = o.w / (1.f + __expf(-o.w));
    *(float4*)&uT[(size_t)d * BL + bl] = o;
}

// ---- chunk-decomposed selective scan ----
// thread mapping (pass 1/3): t = [b:2][d:10][seg:3][n:4]
// Pass 1: local scan with h0=0; emit h_end and sum(delta) per segment.
__global__ __launch_bounds__(256) void scan_part1(const float* __restrict__ deltaT,
        const float* __restrict__ uT, const float* __restrict__ xdbl,
        const float* __restrict__ A_log, float* __restrict__ h_end,
        float* __restrict__ Sdv)
{
    const int t = blockIdx.x * 256 + threadIdx.x;
    const int n = t & 15;
    const int seg = (t >> 4) & (G_ - 1);
    const int d = (t >> 7) & (DI - 1);
    const int b = t >> 17;

    const float Acoef = -__expf(A_log[d * NS + n]);
    float h = 0.f, sdv = 0.f;

    const size_t base_t = (size_t)d * BL + b * L_ + seg * SEG;
    const size_t base_x = (size_t)b * L_ * XDC + (size_t)seg * SEG * XDC;

    for (int l0 = 0; l0 < SEG; l0 += 16) {
        float dv[16], uv[16], Bv[16];
        {
            const float4* dp = (const float4*)(deltaT + base_t + l0);
            const float4* up = (const float4*)(uT + base_t + l0);
            #pragma unroll
            for (int i = 0; i < 4; i++) {
                *(float4*)&dv[i * 4] = dp[i];
                *(float4*)&uv[i * 4] = up[i];
            }
        }
        {
            const float* xp = xdbl + base_x + (size_t)l0 * XDC + 32 + n;
            #pragma unroll
            for (int j = 0; j < 16; j++) Bv[j] = xp[j * XDC];
        }
        #pragma unroll
        for (int j = 0; j < 16; j++) {
            sdv += dv[j];
            Bv[j] *= dv[j] * uv[j];
            dv[j] = __expf(dv[j] * Acoef);
        }
        #pragma unroll
        for (int j = 0; j < 16; j++)
            h = fmaf(dv[j], h, Bv[j]);
    }
    const int si = ((b * DI + d) * G_ + seg);
    h_end[si * NS + n] = h;
    if (n == 0) Sdv[si] = sdv;
}

// Pass 2: serial combine across segments -> per-segment initial state h0.
__global__ __launch_bounds__(256) void scan_part2(const float* __restrict__ h_end,
        const float* __restrict__ Sdv, const float* __restrict__ A_log,
        float* __restrict__ h0)
{
    const int t = blockIdx.x * 256 + threadIdx.x;   // B_*DI*NS
    const int n = t & 15;
    const int g = t >> 4;                            // b*DI + d
    const int d = g & (DI - 1);
    const float Acoef = -__expf(A_log[d * NS + n]);
    float H = 0.f;
    #pragma unroll
    for (int s = 0; s < G_; s++) {
        const int si = g * G_ + s;
        h0[si * NS + n] = H;
        H = h_end[si * NS + n] + __expf(Acoef * Sdv[si]) * H;
    }
}

// Pass 3: full scan per segment from h0, with reduction + gate + yT store.
__global__ __launch_bounds__(256) void scan_part3(const float* __restrict__ deltaT,
        const float* __restrict__ uT, const float* __restrict__ xdbl,
        const float* __restrict__ xzT, const float* __restrict__ A_log,
        const float* __restrict__ Dp, const float* __restrict__ h0,
        float* __restrict__ yT)
{
    const int t = blockIdx.x * 256 + threadIdx.x;
    const int n = t & 15;
    const int seg = (t >> 4) & (G_ - 1);
    const int d = (t >> 7) & (DI - 1);
    const int b = t >> 17;

    const float Acoef = -__expf(A_log[d * NS + n]);
    const float Dd = Dp[d];
    float h = h0[((b * DI + d) * G_ + seg) * NS + n];

    const size_t base_t = (size_t)d * BL + b * L_ + seg * SEG;
    const size_t base_z = (size_t)(DI + d) * BL + b * L_ + seg * SEG;
    const size_t base_x = (size_t)b * L_ * XDC + (size_t)seg * SEG * XDC;

    for (int l0 = 0; l0 < SEG; l0 += 16) {
        float dv[16], uv[16];
        {
            const float4* dp = (const float4*)(deltaT + base_t + l0);
            const float4* up = (const float4*)(uT + base_t + l0);
            #pragma unroll
            for (int i = 0; i < 4; i++) {
                *(float4*)&dv[i * 4] = dp[i];
                *(float4*)&uv[i * 4] = up[i];
            }
        }
        float Bv[16], Cv[16];
        {
            const float* xp = xdbl + base_x + (size_t)l0 * XDC + 32 + n;
            #pragma unroll
            for (int j = 0; j < 16; j++) {
                Bv[j] = xp[j * XDC];
                Cv[j] = xp[j * XDC + 16];
            }
        }
        #pragma unroll
        for (int j = 0; j < 16; j++) {
            Bv[j] *= dv[j] * uv[j];
            dv[j] = __expf(dv[j] * Acoef);
        }
        float p[16];
        #pragma unroll
        for (int j = 0; j < 16; j++) {
            h = fmaf(dv[j], h, Bv[j]);
            p[j] = h * Cv[j];
        }
        #pragma unroll
        for (int m = 1; m <= 8; m <<= 1) {
            #pragma unroll
            for (int j = 0; j < 16; j++)
                p[j] += __shfl_xor(p[j], m);
        }
        if (n == 0) {
            float zv[16];
            const float4* zp = (const float4*)(xzT + base_z + l0);
            #pragma unroll
            for (int i = 0; i < 4; i++) *(float4*)&zv[i * 4] = zp[i];
            float yv[16];
            #pragma unroll
            for (int j = 0; j < 16; j++) {
                float v = p[j] + uv[j] * Dd;
                yv[j] = v * zv[j] / (1.f + __expf(-zv[j]));
            }
            float4* yp = (float4*)(yT + base_t + l0);
            #pragma unroll
            for (int i = 0; i < 4; i++) yp[i] = *(float4*)&yv[i * 4];
        }
    }
}

// yT fp32 [DI][BL] -> yB bf16 [BL][DI], 64x64 LDS tiles.
__global__ __launch_bounds__(256) void transpose_cast(const float* __restrict__ yT,
        ushort* __restrict__ yB)
{
    __shared__ float t[64][65];
    const int bl0 = blockIdx.x * 64, d0 = blockIdx.y * 64;
    const int tid = threadIdx.x;
    #pragma unroll
    for (int i = 0; i < 4; i++) {
        int chunk = tid + i * 256;
        int dr = chunk >> 4, c4 = (chunk & 15) * 4;
        const float4 v = *(const float4*)&yT[(size_t)(d0 + dr) * BL + bl0 + c4];
        t[dr][c4 + 0] = v.x; t[dr][c4 + 1] = v.y;
        t[dr][c4 + 2] = v.z; t[dr][c4 + 3] = v.w;
    }
    __syncthreads();
    #pragma unroll
    for (int i = 0; i < 4; i++) {
        int chunk = tid + i * 256;
        int br = chunk >> 4, dc4 = (chunk & 15) * 4;
        ushort4 o;
        o.x = f2bf(t[dc4 + 0][br]); o.y = f2bf(t[dc4 + 1][br]);
        o.z = f2bf(t[dc4 + 2][br]); o.w = f2bf(t[dc4 + 3][br]);
        *(ushort4*)&yB[(size_t)(bl0 + br) * DI + d0 + dc4] = o;
    }
}

// LayerNorm over last dim (512), one block per row, fp32 out.
__global__ __launch_bounds__(256) void ln_kernel(const float* __restrict__ r,
        const float* __restrict__ lnw, const float* __restrict__ lnb,
        float* __restrict__ out)
{
    int row = blockIdx.x;
    const float* rr = r + (size_t)row * DM;
    float v0 = rr[threadIdx.x], v1 = rr[threadIdx.x + 256];
    float s = v0 + v1, s2 = v0 * v0 + v1 * v1;
    #pragma unroll
    for (int off = 32; off > 0; off >>= 1) {
        s  += __shfl_down(s, off);
        s2 += __shfl_down(s2, off);
    }
    __shared__ float ls[4], ls2[4];
    __shared__ float mu_s, rstd_s;
    int wid = threadIdx.x >> 6, lane = threadIdx.x & 63;
    if (lane == 0) { ls[wid] = s; ls2[wid] = s2; }
    __syncthreads();
    if (threadIdx.x == 0) {
        float S = ls[0] + ls[1] + ls[2] + ls[3];
        float S2 = ls2[0] + ls2[1] + ls2[2] + ls2[3];
        float mu = S * (1.f / DM);
        float var = S2 * (1.f / DM) - mu * mu;
        mu_s = mu;
        rstd_s = rsqrtf(var + 1e-5f);
    }
    __syncthreads();
    float mu = mu_s, rstd = rstd_s;
    out[(size_t)row * DM + threadIdx.x] =
        (v0 - mu) * rstd * lnw[threadIdx.x] + lnb[threadIdx.x];
    out[(size_t)row * DM + threadIdx.x + 256] =
        (v1 - mu) * rstd * lnw[threadIdx.x + 256] + lnb[threadIdx.x + 256];
}

extern "C" void kernel_launch(void* const* d_in, const int* in_sizes, int n_in,
                              void* d_out, int out_size, void* d_ws, size_t ws_size,
                              hipStream_t stream)
{
    const float* x         = (const float*)d_in[0];
    const float* in_proj_w = (const float*)d_in[1];
    const float* conv_w    = (const float*)d_in[2];
    const float* conv_b    = (const float*)d_in[3];
    const float* x_proj_w  = (const float*)d_in[4];
    const float* dt_proj_w = (const float*)d_in[5];
    const float* dt_proj_b = (const float*)d_in[6];
    const float* A_log     = (const float*)d_in[7];
    const float* Dvec      = (const float*)d_in[8];
    const float* out_proj_w= (const float*)d_in[9];
    const float* ln_w      = (const float*)d_in[10];
    const float* ln_b      = (const float*)d_in[11];
    float* out = (float*)d_out;

    // fp32 regions (floats)
    float* ws     = (float*)d_ws;
    float* xzT    = ws;                                  // 2048 x 4096 (32 MB)
    float* uT     = xzT    + (size_t)2048 * BL;          // 1024 x 4096 (16 MB)
    float* xdbl   = uT     + (size_t)DI * BL;            // 4096 x 64   (1 MB)
    float* deltaT = xdbl   + (size_t)BL * XDC;           // 1024 x 4096 (16 MB)
    float* yT     = deltaT + (size_t)DI * BL;            // 1024 x 4096 (16 MB)
    float* r      = yT     + (size_t)DI * BL;            // 4096 x 512  (8 MB)
    // bf16 aliases over time-dead fp32 regions:
    ushort* xB    = (ushort*)yT;                          // dead before scan writes yT
    ushort* yB    = (ushort*)deltaT;                      // deltaT dead after scan
    ushort* wOutB = (ushort*)deltaT + (size_t)4 * 1024 * 1024;
    ushort* wInB  = (ushort*)deltaT + (size_t)9 * 1024 * 1024 / 2;
    // scan summaries live in r (dead until gemm6b): 4.2 MB < 8 MB
    float* h_end  = r;                                   // B*DI*G*NS = 524288 floats
    float* h0     = r + (size_t)B_ * DI * G_ * NS;       // 524288 floats
    float* Sdv    = h0 + (size_t)B_ * DI * G_ * NS;      // B*DI*G = 32768 floats

    dim3 blk(256);

    // 0) casts for gemm1
    cast_bf16<<<(BL * DM / 4 + 255) / 256, blk, 0, stream>>>(x, xB, BL * DM / 4);
    cast_bf16<<<(2048 * DM / 4 + 255) / 256, blk, 0, stream>>>(in_proj_w, wInB, 2048 * DM / 4);

    // 1) xzT[e][bl] = in_proj_w @ x^T : M=2048, N=4096, K=512 (MFMA)
    gemm_mfma<0><<<dim3(BL / 128, 2048 / 128), blk, 0, stream>>>(
        wInB, xB, xzT, DM, BL, nullptr);

    // 2) uT = silu(causal_conv(xsT) + cb)
    conv_silu<<<(DI * BL / 4) / 256, blk, 0, stream>>>(xzT, conv_w, conv_b, uT);

    // 3) xdbl = u @ x_proj_w^T : M=4096 (MT=32), N=64, K=1024
    gemm_tn<32><<<dim3(1, BL / 32), blk, 0, stream>>>(
        uT, x_proj_w, xdbl, XDC, DI, BL, DI, XDC, 1, 0, nullptr);

    // 4) deltaT = softplus(dt_proj_w @ dt^T + b[m]) : M=1024, N=4096, K=32
    gemm_tn<128><<<dim3(BL / 64, DI / 128), blk, 0, stream>>>(
        dt_proj_w, xdbl, deltaT, BL, 32, 32, XDC, BL, 0, 3, dt_proj_b);

    // 5) chunk-decomposed selective scan + gate
    scan_part1<<<(B_ * DI * G_ * NS) / 256, blk, 0, stream>>>(
        deltaT, uT, xdbl, A_log, h_end, Sdv);
    scan_part2<<<(B_ * DI * NS) / 256, blk, 0, stream>>>(
        h_end, Sdv, A_log, h0);
    scan_part3<<<(B_ * DI * G_ * NS) / 256, blk, 0, stream>>>(
        deltaT, uT, xdbl, xzT, A_log, Dvec, h0, yT);

    // 6a) yT -> yB (bf16, [bl][d]); cast out_proj_w
    transpose_cast<<<dim3(BL / 64, DI / 64), blk, 0, stream>>>(yT, yB);
    cast_bf16<<<(DM * DI / 4 + 255) / 256, blk, 0, stream>>>(out_proj_w, wOutB, DM * DI / 4);

    // 6b) r[bl][dm] = y @ out_proj_w^T + x : M=4096, N=512, K=1024 (MFMA, resid epi)
    gemm_mfma<2><<<dim3(DM / 128, BL / 128), blk, 0, stream>>>(
        yB, wOutB, r, DI, DM, x);

    // 7) LayerNorm -> fp32 out
    ln_kernel<<<BL, blk, 0, stream>>>(r, ln_w, ln_b, out);
}

// Round 8
// 303.360 us; speedup vs baseline: 1.9464x; 1.0593x over previous
//
#include <hip/hip_runtime.h>
#include <hip/hip_bf16.h>
#include <math.h>

// MambaBlock: B=4, L=1024, D_MODEL=512, D_INNER=1024, D_STATE=16, D_CONV=4, DT_RANK=32
// fp32 in/out. bf16 MFMA for the two big GEMMs; fp32 SIMT for the small ones.
// Scan: 3-pass chunk-decomposed (G=8 segments); pass 3 uses a halving butterfly
// so lane n ends owning timestep l0+n's sum -> parallel gate + coalesced store.
#define B_   4
#define L_   1024
#define DM   512
#define DI   1024
#define NS   16
#define XDC  64      // DT_RANK + 2*D_STATE
#define BL   4096    // B_*L_
#define G_   8       // scan segments
#define SEG  128     // L_/G_

typedef short bfrag __attribute__((ext_vector_type(8)));   // 8 bf16
typedef float ffrag __attribute__((ext_vector_type(4)));   // 4 fp32 acc

__device__ __forceinline__ ushort f2bf(float v) {
    __hip_bfloat16 h = __float2bfloat16(v);
    return *(ushort*)&h;
}

// fp32 -> bf16 cast, 4 elems/thread
__global__ __launch_bounds__(256) void cast_bf16(const float* __restrict__ in,
        ushort* __restrict__ out, int n4)
{
    int i = blockIdx.x * 256 + threadIdx.x;
    if (i >= n4) return;
    float4 v = ((const float4*)in)[i];
    ushort4 o;
    o.x = f2bf(v.x); o.y = f2bf(v.y); o.z = f2bf(v.z); o.w = f2bf(v.w);
    ((ushort4*)out)[i] = o;
}

// MFMA bf16 TN GEMM: C[M,N] = A[M,K] * B[N,K]^T, fp32 out.
// 128x128 block tile, BK=32, 4 waves (2x2), wave tile 64x64 (4x4 of 16x16x32).
// EPI: 0 none; 2 C += resid[m*ldc+n]
template<int EPI>
__global__ __launch_bounds__(256) void gemm_mfma(const ushort* __restrict__ A,
        const ushort* __restrict__ B, float* __restrict__ C,
        int K, int ldc, const float* __restrict__ resid)
{
    __shared__ ushort As[128][40];
    __shared__ ushort Bs[128][40];
    const int tid = threadIdx.x;
    const int lane = tid & 63, wave = tid >> 6;
    const int wm = (wave & 1) * 64, wn = (wave >> 1) * 64;
    const int l15 = lane & 15, quad = lane >> 4;
    const int m0 = blockIdx.y * 128, n0 = blockIdx.x * 128;

    ffrag acc[4][4] = {};

    for (int k0 = 0; k0 < K; k0 += 32) {
        #pragma unroll
        for (int i = 0; i < 2; i++) {
            int chunk = tid + i * 256;
            int row = chunk >> 2, kk8 = (chunk & 3) * 8;
            *(uint4*)&As[row][kk8] = *(const uint4*)&A[(size_t)(m0 + row) * K + k0 + kk8];
            *(uint4*)&Bs[row][kk8] = *(const uint4*)&B[(size_t)(n0 + row) * K + k0 + kk8];
        }
        __syncthreads();
        bfrag af[4], bfv[4];
        #pragma unroll
        for (int i = 0; i < 4; i++) {
            af[i]  = *(const bfrag*)&As[wm + i * 16 + l15][quad * 8];
            bfv[i] = *(const bfrag*)&Bs[wn + i * 16 + l15][quad * 8];
        }
        #pragma unroll
        for (int i = 0; i < 4; i++)
            #pragma unroll
            for (int j = 0; j < 4; j++)
                acc[i][j] = __builtin_amdgcn_mfma_f32_16x16x32_bf16(af[i], bfv[j], acc[i][j], 0, 0, 0);
        __syncthreads();
    }

    #pragma unroll
    for (int i = 0; i < 4; i++) {
        #pragma unroll
        for (int j = 0; j < 4; j++) {
            int n = n0 + wn + j * 16 + l15;
            #pragma unroll
            for (int r = 0; r < 4; r++) {
                int m = m0 + wm + i * 16 + quad * 4 + r;
                float v = acc[i][j][r];
                if (EPI == 2) v += resid[(size_t)m * ldc + n];
                C[(size_t)m * ldc + n] = v;
            }
        }
    }
}

// SIMT fp32 GEMM: C[M,N] = A * W^T. MT x 64 tile.
// epi: 0 none; 3 softplus(v + bias[m])
template<int MT>
__global__ __launch_bounds__(256) void gemm_tn(const float* __restrict__ A,
        const float* __restrict__ W, float* __restrict__ C,
        int N, int K, int lda, int ldw, int ldc, int atrans,
        int epi, const float* __restrict__ bias)
{
    __shared__ float As[16][MT + 4];
    __shared__ float Ws[16][68];
    const int tid = threadIdx.x;
    const int tx = tid & 15, ty = tid >> 4;
    const int n0 = blockIdx.x * 64, m0 = blockIdx.y * MT;
    const int RM = MT / 16;
    float acc[RM][4] = {};

    for (int k0 = 0; k0 < K; k0 += 16) {
        const int nchunk = MT * 4;
        if (atrans) {
            #pragma unroll
            for (int i = 0; i < (nchunk + 255) / 256; i++) {
                int idx = tid + i * 256;
                if (nchunk < 256 * (i + 1) && idx >= nchunk) break;
                int k = idx / (MT / 4), m4 = (idx % (MT / 4)) * 4;
                const float4 v = *(const float4*)&A[(size_t)(k0 + k) * lda + m0 + m4];
                As[k][m4 + 0] = v.x; As[k][m4 + 1] = v.y;
                As[k][m4 + 2] = v.z; As[k][m4 + 3] = v.w;
            }
        } else {
            #pragma unroll
            for (int i = 0; i < (nchunk + 255) / 256; i++) {
                int idx = tid + i * 256;
                if (nchunk < 256 * (i + 1) && idx >= nchunk) break;
                int r = idx >> 2, c4 = (idx & 3) * 4;
                const float4 v = *(const float4*)&A[(size_t)(m0 + r) * lda + k0 + c4];
                As[c4 + 0][r] = v.x; As[c4 + 1][r] = v.y;
                As[c4 + 2][r] = v.z; As[c4 + 3][r] = v.w;
            }
        }
        {
            int r = tid >> 2, c4 = (tid & 3) * 4;
            const float4 v = *(const float4*)&W[(size_t)(n0 + r) * ldw + k0 + c4];
            Ws[c4 + 0][r] = v.x; Ws[c4 + 1][r] = v.y;
            Ws[c4 + 2][r] = v.z; Ws[c4 + 3][r] = v.w;
        }
        __syncthreads();
        #pragma unroll
        for (int kk = 0; kk < 16; kk++) {
            float a[RM], b[4];
            #pragma unroll
            for (int i = 0; i < RM; i++) a[i] = As[kk][ty * RM + i];
            #pragma unroll
            for (int j = 0; j < 4; j++) b[j] = Ws[kk][tx * 4 + j];
            #pragma unroll
            for (int i = 0; i < RM; i++)
                #pragma unroll
                for (int j = 0; j < 4; j++)
                    acc[i][j] = fmaf(a[i], b[j], acc[i][j]);
        }
        __syncthreads();
    }

    #pragma unroll
    for (int i = 0; i < RM; i++) {
        int m = m0 + ty * RM + i;
        int nb = n0 + tx * 4;
        float4 v = make_float4(acc[i][0], acc[i][1], acc[i][2], acc[i][3]);
        if (epi == 3) {
            float bm = bias[m];
            v.x += bm; v.y += bm; v.z += bm; v.w += bm;
            v.x = (v.x > 20.f) ? v.x : log1pf(__expf(v.x));
            v.y = (v.y > 20.f) ? v.y : log1pf(__expf(v.y));
            v.z = (v.z > 20.f) ? v.z : log1pf(__expf(v.z));
            v.w = (v.w > 20.f) ? v.w : log1pf(__expf(v.w));
        }
        *(float4*)&C[(size_t)m * ldc + nb] = v;
    }
}

// depthwise causal conv (k=4) + bias + SiLU, channel-major, 4 outputs/thread.
__global__ __launch_bounds__(256) void conv_silu(const float* __restrict__ xzT,
        const float* __restrict__ cw, const float* __restrict__ cb,
        float* __restrict__ uT)
{
    int i = blockIdx.x * 256 + threadIdx.x;     // over DI*BL/4
    int d  = i >> 10;
    int q  = i & 1023;
    int bl = q * 4;
    int l  = bl & (L_ - 1);
    const float* row = xzT + (size_t)d * BL;
    float4 cur = *(const float4*)&row[bl];
    float4 prev = make_float4(0.f, 0.f, 0.f, 0.f);
    if (l != 0) prev = *(const float4*)&row[bl - 4];
    float v[7] = { prev.y, prev.z, prev.w, cur.x, cur.y, cur.z, cur.w };
    float w0 = cw[d * 4 + 0], w1 = cw[d * 4 + 1], w2 = cw[d * 4 + 2], w3 = cw[d * 4 + 3];
    float bias = cb[d];
    float4 o;
    o.x = bias + w0 * v[0] + w1 * v[1] + w2 * v[2] + w3 * v[3];
    o.y = bias + w0 * v[1] + w1 * v[2] + w2 * v[3] + w3 * v[4];
    o.z = bias + w0 * v[2] + w1 * v[3] + w2 * v[4] + w3 * v[5];
    o.w = bias + w0 * v[3] + w1 * v[4] + w2 * v[5] + w3 * v[6];
    o.x = o.x / (1.f + __expf(-o.x));
    o.y = o.y / (1.f + __expf(-o.y));
    o.z = o.z / (1.f + __expf(-o.z));
    o.w = o.w / (1.f + __expf(-o.w));
    *(float4*)&uT[(size_t)d * BL + bl] = o;
}

// ---- chunk-decomposed selective scan ----
// thread mapping (pass 1/3): t = [b:2][d:10][seg:3][n:4]
// Pass 1: local scan with h0=0; emit h_end and sum(delta) per segment.
__global__ __launch_bounds__(256) void scan_part1(const float* __restrict__ deltaT,
        const float* __restrict__ uT, const float* __restrict__ xdbl,
        const float* __restrict__ A_log, float* __restrict__ h_end,
        float* __restrict__ Sdv)
{
    const int t = blockIdx.x * 256 + threadIdx.x;
    const int n = t & 15;
    const int seg = (t >> 4) & (G_ - 1);
    const int d = (t >> 7) & (DI - 1);
    const int b = t >> 17;

    const float Acoef = -__expf(A_log[d * NS + n]);
    float h = 0.f, sdv = 0.f;

    const size_t base_t = (size_t)d * BL + b * L_ + seg * SEG;
    const size_t base_x = (size_t)b * L_ * XDC + (size_t)seg * SEG * XDC;

    for (int l0 = 0; l0 < SEG; l0 += 16) {
        float dv[16], uv[16], Bv[16];
        {
            const float4* dp = (const float4*)(deltaT + base_t + l0);
            const float4* up = (const float4*)(uT + base_t + l0);
            #pragma unroll
            for (int i = 0; i < 4; i++) {
                *(float4*)&dv[i * 4] = dp[i];
                *(float4*)&uv[i * 4] = up[i];
            }
        }
        {
            const float* xp = xdbl + base_x + (size_t)l0 * XDC + 32 + n;
            #pragma unroll
            for (int j = 0; j < 16; j++) Bv[j] = xp[j * XDC];
        }
        #pragma unroll
        for (int j = 0; j < 16; j++) {
            sdv += dv[j];
            Bv[j] *= dv[j] * uv[j];
            dv[j] = __expf(dv[j] * Acoef);
        }
        #pragma unroll
        for (int j = 0; j < 16; j++)
            h = fmaf(dv[j], h, Bv[j]);
    }
    const int si = ((b * DI + d) * G_ + seg);
    h_end[si * NS + n] = h;
    if (n == 0) Sdv[si] = sdv;
}

// Pass 2: serial combine across segments -> per-segment initial state h0.
__global__ __launch_bounds__(256) void scan_part2(const float* __restrict__ h_end,
        const float* __restrict__ Sdv, const float* __restrict__ A_log,
        float* __restrict__ h0)
{
    const int t = blockIdx.x * 256 + threadIdx.x;   // B_*DI*NS
    const int n = t & 15;
    const int g = t >> 4;                            // b*DI + d
    const int d = g & (DI - 1);
    const float Acoef = -__expf(A_log[d * NS + n]);
    float H = 0.f;
    #pragma unroll
    for (int s = 0; s < G_; s++) {
        const int si = g * G_ + s;
        h0[si * NS + n] = H;
        H = h_end[si * NS + n] + __expf(Acoef * Sdv[si]) * H;
    }
}

// Pass 3: scan per segment from h0. Halving butterfly: lane n ends with the
// full 16-lane sum for timestep l0+n -> parallel gate, coalesced dword store.
__global__ __launch_bounds__(256) void scan_part3(const float* __restrict__ deltaT,
        const float* __restrict__ uT, const float* __restrict__ xdbl,
        const float* __restrict__ xzT, const float* __restrict__ A_log,
        const float* __restrict__ Dp, const float* __restrict__ h0,
        float* __restrict__ yT)
{
    const int t = blockIdx.x * 256 + threadIdx.x;
    const int n = t & 15;
    const int seg = (t >> 4) & (G_ - 1);
    const int d = (t >> 7) & (DI - 1);
    const int b = t >> 17;

    const float Acoef = -__expf(A_log[d * NS + n]);
    const float Dd = Dp[d];
    float h = h0[((b * DI + d) * G_ + seg) * NS + n];

    const size_t base_t = (size_t)d * BL + b * L_ + seg * SEG;
    const size_t base_z = (size_t)(DI + d) * BL + b * L_ + seg * SEG;
    const size_t base_x = (size_t)b * L_ * XDC + (size_t)seg * SEG * XDC;

    for (int l0 = 0; l0 < SEG; l0 += 16) {
        // gate operands for this lane's owned timestep (l0+n): issue early
        float ug = uT [base_t + l0 + n];
        float zg = xzT[base_z + l0 + n];

        float dv[16], uv[16];
        {
            const float4* dp = (const float4*)(deltaT + base_t + l0);
            const float4* up = (const float4*)(uT + base_t + l0);
            #pragma unroll
            for (int i = 0; i < 4; i++) {
                *(float4*)&dv[i * 4] = dp[i];
                *(float4*)&uv[i * 4] = up[i];
            }
        }
        float Bv[16], Cv[16];
        {
            const float* xp = xdbl + base_x + (size_t)l0 * XDC + 32 + n;
            #pragma unroll
            for (int j = 0; j < 16; j++) {
                Bv[j] = xp[j * XDC];
                Cv[j] = xp[j * XDC + 16];
            }
        }
        #pragma unroll
        for (int j = 0; j < 16; j++) {
            Bv[j] *= dv[j] * uv[j];
            dv[j] = __expf(dv[j] * Acoef);
        }
        float p[16];
        #pragma unroll
        for (int j = 0; j < 16; j++) {
            h = fmaf(dv[j], h, Bv[j]);
            p[j] = h * Cv[j];
        }

        // halving butterfly: final owner of timestep j is lane n=j.
        float q8[8];
        #pragma unroll
        for (int k = 0; k < 8; k++) {
            float tt = (n & 8) ? p[k] : p[k + 8];
            float rr = __shfl_xor(tt, 8);
            q8[k] = ((n & 8) ? p[k + 8] : p[k]) + rr;
        }
        float q4[4];
        #pragma unroll
        for (int k = 0; k < 4; k++) {
            float tt = (n & 4) ? q8[k] : q8[k + 4];
            float rr = __shfl_xor(tt, 4);
            q4[k] = ((n & 4) ? q8[k + 4] : q8[k]) + rr;
        }
        float q2[2];
        #pragma unroll
        for (int k = 0; k < 2; k++) {
            float tt = (n & 2) ? q4[k] : q4[k + 2];
            float rr = __shfl_xor(tt, 2);
            q2[k] = ((n & 2) ? q4[k + 2] : q4[k]) + rr;
        }
        float tt = (n & 1) ? q2[0] : q2[1];
        float rr = __shfl_xor(tt, 1);
        float S = ((n & 1) ? q2[1] : q2[0]) + rr;

        // gate + store (all 16 lanes, one timestep each, coalesced)
        float v = S + ug * Dd;
        v *= zg / (1.f + __expf(-zg));
        yT[base_t + l0 + n] = v;
    }
}

// yT fp32 [DI][BL] -> yB bf16 [BL][DI], 64x64 LDS tiles.
__global__ __launch_bounds__(256) void transpose_cast(const float* __restrict__ yT,
        ushort* __restrict__ yB)
{
    __shared__ float t[64][65];
    const int bl0 = blockIdx.x * 64, d0 = blockIdx.y * 64;
    const int tid = threadIdx.x;
    #pragma unroll
    for (int i = 0; i < 4; i++) {
        int chunk = tid + i * 256;
        int dr = chunk >> 4, c4 = (chunk & 15) * 4;
        const float4 v = *(const float4*)&yT[(size_t)(d0 + dr) * BL + bl0 + c4];
        t[dr][c4 + 0] = v.x; t[dr][c4 + 1] = v.y;
        t[dr][c4 + 2] = v.z; t[dr][c4 + 3] = v.w;
    }
    __syncthreads();
    #pragma unroll
    for (int i = 0; i < 4; i++) {
        int chunk = tid + i * 256;
        int br = chunk >> 4, dc4 = (chunk & 15) * 4;
        ushort4 o;
        o.x = f2bf(t[dc4 + 0][br]); o.y = f2bf(t[dc4 + 1][br]);
        o.z = f2bf(t[dc4 + 2][br]); o.w = f2bf(t[dc4 + 3][br]);
        *(ushort4*)&yB[(size_t)(bl0 + br) * DI + d0 + dc4] = o;
    }
}

// LayerNorm over last dim (512), one block per row, fp32 out.
__global__ __launch_bounds__(256) void ln_kernel(const float* __restrict__ r,
        const float* __restrict__ lnw, const float* __restrict__ lnb,
        float* __restrict__ out)
{
    int row = blockIdx.x;
    const float* rr = r + (size_t)row * DM;
    float v0 = rr[threadIdx.x], v1 = rr[threadIdx.x + 256];
    float s = v0 + v1, s2 = v0 * v0 + v1 * v1;
    #pragma unroll
    for (int off = 32; off > 0; off >>= 1) {
        s  += __shfl_down(s, off);
        s2 += __shfl_down(s2, off);
    }
    __shared__ float ls[4], ls2[4];
    __shared__ float mu_s, rstd_s;
    int wid = threadIdx.x >> 6, lane = threadIdx.x & 63;
    if (lane == 0) { ls[wid] = s; ls2[wid] = s2; }
    __syncthreads();
    if (threadIdx.x == 0) {
        float S = ls[0] + ls[1] + ls[2] + ls[3];
        float S2 = ls2[0] + ls2[1] + ls2[2] + ls2[3];
        float mu = S * (1.f / DM);
        float var = S2 * (1.f / DM) - mu * mu;
        mu_s = mu;
        rstd_s = rsqrtf(var + 1e-5f);
    }
    __syncthreads();
    float mu = mu_s, rstd = rstd_s;
    out[(size_t)row * DM + threadIdx.x] =
        (v0 - mu) * rstd * lnw[threadIdx.x] + lnb[threadIdx.x];
    out[(size_t)row * DM + threadIdx.x + 256] =
        (v1 - mu) * rstd * lnw[threadIdx.x + 256] + lnb[threadIdx.x + 256];
}

extern "C" void kernel_launch(void* const* d_in, const int* in_sizes, int n_in,
                              void* d_out, int out_size, void* d_ws, size_t ws_size,
                              hipStream_t stream)
{
    const float* x         = (const float*)d_in[0];
    const float* in_proj_w = (const float*)d_in[1];
    const float* conv_w    = (const float*)d_in[2];
    const float* conv_b    = (const float*)d_in[3];
    const float* x_proj_w  = (const float*)d_in[4];
    const float* dt_proj_w = (const float*)d_in[5];
    const float* dt_proj_b = (const float*)d_in[6];
    const float* A_log     = (const float*)d_in[7];
    const float* Dvec      = (const float*)d_in[8];
    const float* out_proj_w= (const float*)d_in[9];
    const float* ln_w      = (const float*)d_in[10];
    const float* ln_b      = (const float*)d_in[11];
    float* out = (float*)d_out;

    // fp32 regions (floats)
    float* ws     = (float*)d_ws;
    float* xzT    = ws;                                  // 2048 x 4096 (32 MB)
    float* uT     = xzT    + (size_t)2048 * BL;          // 1024 x 4096 (16 MB)
    float* xdbl   = uT     + (size_t)DI * BL;            // 4096 x 64   (1 MB)
    float* deltaT = xdbl   + (size_t)BL * XDC;           // 1024 x 4096 (16 MB)
    float* yT     = deltaT + (size_t)DI * BL;            // 1024 x 4096 (16 MB)
    float* r      = yT     + (size_t)DI * BL;            // 4096 x 512  (8 MB)
    // bf16 aliases over time-dead fp32 regions:
    ushort* xB    = (ushort*)yT;                          // dead before scan writes yT
    ushort* yB    = (ushort*)deltaT;                      // deltaT dead after scan
    ushort* wOutB = (ushort*)deltaT + (size_t)4 * 1024 * 1024;
    ushort* wInB  = (ushort*)deltaT + (size_t)9 * 1024 * 1024 / 2;
    // scan summaries live in r (dead until gemm6b)
    float* h_end  = r;                                   // B*DI*G*NS = 524288 floats
    float* h0     = r + (size_t)B_ * DI * G_ * NS;       // 524288 floats
    float* Sdv    = h0 + (size_t)B_ * DI * G_ * NS;      // B*DI*G = 32768 floats

    dim3 blk(256);

    // 0) casts for gemm1
    cast_bf16<<<(BL * DM / 4 + 255) / 256, blk, 0, stream>>>(x, xB, BL * DM / 4);
    cast_bf16<<<(2048 * DM / 4 + 255) / 256, blk, 0, stream>>>(in_proj_w, wInB, 2048 * DM / 4);

    // 1) xzT[e][bl] = in_proj_w @ x^T : M=2048, N=4096, K=512 (MFMA)
    gemm_mfma<0><<<dim3(BL / 128, 2048 / 128), blk, 0, stream>>>(
        wInB, xB, xzT, DM, BL, nullptr);

    // 2) uT = silu(causal_conv(xsT) + cb)
    conv_silu<<<(DI * BL / 4) / 256, blk, 0, stream>>>(xzT, conv_w, conv_b, uT);

    // 3) xdbl = u @ x_proj_w^T : M=4096 (MT=32), N=64, K=1024
    gemm_tn<32><<<dim3(1, BL / 32), blk, 0, stream>>>(
        uT, x_proj_w, xdbl, XDC, DI, BL, DI, XDC, 1, 0, nullptr);

    // 4) deltaT = softplus(dt_proj_w @ dt^T + b[m]) : M=1024, N=4096, K=32
    gemm_tn<128><<<dim3(BL / 64, DI / 128), blk, 0, stream>>>(
        dt_proj_w, xdbl, deltaT, BL, 32, 32, XDC, BL, 0, 3, dt_proj_b);

    // 5) chunk-decomposed selective scan + gate
    scan_part1<<<(B_ * DI * G_ * NS) / 256, blk, 0, stream>>>(
        deltaT, uT, xdbl, A_log, h_end, Sdv);
    scan_part2<<<(B_ * DI * NS) / 256, blk, 0, stream>>>(
        h_end, Sdv, A_log, h0);
    scan_part3<<<(B_ * DI * G_ * NS) / 256, blk, 0, stream>>>(
        deltaT, uT, xdbl, xzT, A_log, Dvec, h0, yT);

    // 6a) yT -> yB (bf16, [bl][d]); cast out_proj_w
    transpose_cast<<<dim3(BL / 64, DI / 64), blk, 0, stream>>>(yT, yB);
    cast_bf16<<<(DM * DI / 4 + 255) / 256, blk, 0, stream>>>(out_proj_w, wOutB, DM * DI / 4);

    // 6b) r[bl][dm] = y @ out_proj_w^T + x : M=4096, N=512, K=1024 (MFMA, resid epi)
    gemm_mfma<2><<<dim3(DM / 128, BL / 128), blk, 0, stream>>>(
        yB, wOutB, r, DI, DM, x);

    // 7) LayerNorm -> fp32 out
    ln_kernel<<<BL, blk, 0, stream>>>(r, ln_w, ln_b, out);
}

// Round 9
// 271.071 us; speedup vs baseline: 2.1783x; 1.1191x over previous
//
#include <hip/hip_runtime.h>
#include <hip/hip_bf16.h>
#include <math.h>

// MambaBlock: B=4, L=1024, D_MODEL=512, D_INNER=1024, D_STATE=16, D_CONV=4, DT_RANK=32
// fp32 in/out. bf16 MFMA for the two big GEMMs; fp32 SIMT elsewhere.
// Scan: 3-pass chunk-decomposed (G=16 segments), halving butterfly in pass 3.
// gemm3 (x_dbl): split-K (KS=4) partials + reduce for wave parallelism.
#define B_   4
#define L_   1024
#define DM   512
#define DI   1024
#define NS   16
#define XDC  64      // DT_RANK + 2*D_STATE
#define BL   4096    // B_*L_
#define G_   16      // scan segments
#define SEG  64      // L_/G_
#define KS   4       // gemm3 split-K factor

typedef short bfrag __attribute__((ext_vector_type(8)));   // 8 bf16
typedef float ffrag __attribute__((ext_vector_type(4)));   // 4 fp32 acc

__device__ __forceinline__ ushort f2bf(float v) {
    __hip_bfloat16 h = __float2bfloat16(v);
    return *(ushort*)&h;
}

// fp32 -> bf16 cast, 4 elems/thread
__global__ __launch_bounds__(256) void cast_bf16(const float* __restrict__ in,
        ushort* __restrict__ out, int n4)
{
    int i = blockIdx.x * 256 + threadIdx.x;
    if (i >= n4) return;
    float4 v = ((const float4*)in)[i];
    ushort4 o;
    o.x = f2bf(v.x); o.y = f2bf(v.y); o.z = f2bf(v.z); o.w = f2bf(v.w);
    ((ushort4*)out)[i] = o;
}

// MFMA bf16 TN GEMM: C[M,N] = A[M,K] * B[N,K]^T, fp32 out.
// 128x128 block tile, BK=32, 4 waves (2x2), wave tile 64x64 (4x4 of 16x16x32).
// EPI: 0 none; 2 C += resid[m*ldc+n]
template<int EPI>
__global__ __launch_bounds__(256) void gemm_mfma(const ushort* __restrict__ A,
        const ushort* __restrict__ B, float* __restrict__ C,
        int K, int ldc, const float* __restrict__ resid)
{
    __shared__ ushort As[128][40];
    __shared__ ushort Bs[128][40];
    const int tid = threadIdx.x;
    const int lane = tid & 63, wave = tid >> 6;
    const int wm = (wave & 1) * 64, wn = (wave >> 1) * 64;
    const int l15 = lane & 15, quad = lane >> 4;
    const int m0 = blockIdx.y * 128, n0 = blockIdx.x * 128;

    ffrag acc[4][4] = {};

    for (int k0 = 0; k0 < K; k0 += 32) {
        #pragma unroll
        for (int i = 0; i < 2; i++) {
            int chunk = tid + i * 256;
            int row = chunk >> 2, kk8 = (chunk & 3) * 8;
            *(uint4*)&As[row][kk8] = *(const uint4*)&A[(size_t)(m0 + row) * K + k0 + kk8];
            *(uint4*)&Bs[row][kk8] = *(const uint4*)&B[(size_t)(n0 + row) * K + k0 + kk8];
        }
        __syncthreads();
        bfrag af[4], bfv[4];
        #pragma unroll
        for (int i = 0; i < 4; i++) {
            af[i]  = *(const bfrag*)&As[wm + i * 16 + l15][quad * 8];
            bfv[i] = *(const bfrag*)&Bs[wn + i * 16 + l15][quad * 8];
        }
        #pragma unroll
        for (int i = 0; i < 4; i++)
            #pragma unroll
            for (int j = 0; j < 4; j++)
                acc[i][j] = __builtin_amdgcn_mfma_f32_16x16x32_bf16(af[i], bfv[j], acc[i][j], 0, 0, 0);
        __syncthreads();
    }

    #pragma unroll
    for (int i = 0; i < 4; i++) {
        #pragma unroll
        for (int j = 0; j < 4; j++) {
            int n = n0 + wn + j * 16 + l15;
            #pragma unroll
            for (int r = 0; r < 4; r++) {
                int m = m0 + wm + i * 16 + quad * 4 + r;
                float v = acc[i][j][r];
                if (EPI == 2) v += resid[(size_t)m * ldc + n];
                C[(size_t)m * ldc + n] = v;
            }
        }
    }
}

// SIMT fp32 GEMM (used for gemm4): C[M,N] = A * W^T, A row-major [M,K].
// epi: 3 softplus(v + bias[m])
__global__ __launch_bounds__(256) void gemm_tn128(const float* __restrict__ A,
        const float* __restrict__ W, float* __restrict__ C,
        int N, int K, int lda, int ldw, int ldc,
        const float* __restrict__ bias)
{
    __shared__ float As[16][132];
    __shared__ float Ws[16][68];
    const int tid = threadIdx.x;
    const int tx = tid & 15, ty = tid >> 4;
    const int n0 = blockIdx.x * 64, m0 = blockIdx.y * 128;
    float acc[8][4] = {};

    for (int k0 = 0; k0 < K; k0 += 16) {
        #pragma unroll
        for (int i = 0; i < 2; i++) {
            int idx = tid * 2 + i;
            int r = idx >> 2, c4 = (idx & 3) * 4;
            const float4 v = *(const float4*)&A[(size_t)(m0 + r) * lda + k0 + c4];
            As[c4 + 0][r] = v.x; As[c4 + 1][r] = v.y;
            As[c4 + 2][r] = v.z; As[c4 + 3][r] = v.w;
        }
        {
            int r = tid >> 2, c4 = (tid & 3) * 4;
            const float4 v = *(const float4*)&W[(size_t)(n0 + r) * ldw + k0 + c4];
            Ws[c4 + 0][r] = v.x; Ws[c4 + 1][r] = v.y;
            Ws[c4 + 2][r] = v.z; Ws[c4 + 3][r] = v.w;
        }
        __syncthreads();
        #pragma unroll
        for (int kk = 0; kk < 16; kk++) {
            float a[8], b[4];
            #pragma unroll
            for (int i = 0; i < 8; i++) a[i] = As[kk][ty * 8 + i];
            #pragma unroll
            for (int j = 0; j < 4; j++) b[j] = Ws[kk][tx * 4 + j];
            #pragma unroll
            for (int i = 0; i < 8; i++)
                #pragma unroll
                for (int j = 0; j < 4; j++)
                    acc[i][j] = fmaf(a[i], b[j], acc[i][j]);
        }
        __syncthreads();
    }

    #pragma unroll
    for (int i = 0; i < 8; i++) {
        int m = m0 + ty * 8 + i;
        int nb = n0 + tx * 4;
        float4 v = make_float4(acc[i][0], acc[i][1], acc[i][2], acc[i][3]);
        float bm = bias[m];
        v.x += bm; v.y += bm; v.z += bm; v.w += bm;
        v.x = (v.x > 20.f) ? v.x : log1pf(__expf(v.x));
        v.y = (v.y > 20.f) ? v.y : log1pf(__expf(v.y));
        v.z = (v.z > 20.f) ? v.z : log1pf(__expf(v.z));
        v.w = (v.w > 20.f) ? v.w : log1pf(__expf(v.w));
        *(float4*)&C[(size_t)m * ldc + nb] = v;
    }
}

// gemm3 split-K: part[ks][m][n] = sum over K-chunk ks of u[m][k]*W[n][k].
// A = uT [K=DI][M=BL] (transposed), W = x_proj_w [64][DI].
// Block: 32 m-rows x 64 n-cols, K-chunk = DI/KS = 256, BK=16.
__global__ __launch_bounds__(256) void gemm3_splitk(const float* __restrict__ uT,
        const float* __restrict__ xw, float* __restrict__ part)
{
    __shared__ float As[16][33];    // [k][m] 32 m
    __shared__ float Ws[16][68];    // [k][n] 64 n
    const int tid = threadIdx.x;
    const int tx = tid & 15, ty = tid >> 4;
    const int ks = blockIdx.x, m0 = blockIdx.y * 32;
    const int kbase = ks * (DI / KS);
    float acc[2][4] = {};

    for (int k0 = 0; k0 < DI / KS; k0 += 16) {
        if (tid < 128) {
            int k = tid >> 3, m4 = (tid & 7) * 4;
            const float4 v = *(const float4*)&uT[(size_t)(kbase + k0 + k) * BL + m0 + m4];
            As[k][m4 + 0] = v.x; As[k][m4 + 1] = v.y;
            As[k][m4 + 2] = v.z; As[k][m4 + 3] = v.w;
        }
        {
            int r = tid >> 2, c4 = (tid & 3) * 4;
            const float4 v = *(const float4*)&xw[(size_t)r * DI + kbase + k0 + c4];
            Ws[c4 + 0][r] = v.x; Ws[c4 + 1][r] = v.y;
            Ws[c4 + 2][r] = v.z; Ws[c4 + 3][r] = v.w;
        }
        __syncthreads();
        #pragma unroll
        for (int kk = 0; kk < 16; kk++) {
            float a[2], b[4];
            a[0] = As[kk][ty * 2 + 0];
            a[1] = As[kk][ty * 2 + 1];
            #pragma unroll
            for (int j = 0; j < 4; j++) b[j] = Ws[kk][tx * 4 + j];
            #pragma unroll
            for (int i = 0; i < 2; i++)
                #pragma unroll
                for (int j = 0; j < 4; j++)
                    acc[i][j] = fmaf(a[i], b[j], acc[i][j]);
        }
        __syncthreads();
    }

    float* pp = part + (size_t)ks * BL * XDC;
    #pragma unroll
    for (int i = 0; i < 2; i++) {
        int m = m0 + ty * 2 + i;
        *(float4*)&pp[(size_t)m * XDC + tx * 4] =
            make_float4(acc[i][0], acc[i][1], acc[i][2], acc[i][3]);
    }
}

// reduce KS partials -> xdbl
__global__ __launch_bounds__(256) void gemm3_reduce(const float* __restrict__ part,
        float* __restrict__ xdbl)
{
    int i = blockIdx.x * 256 + threadIdx.x;     // over BL*XDC/4
    const float4* p0 = (const float4*)part;
    float4 a = p0[i];
    #pragma unroll
    for (int s = 1; s < KS; s++) {
        float4 b = p0[i + (size_t)s * BL * XDC / 4];
        a.x += b.x; a.y += b.y; a.z += b.z; a.w += b.w;
    }
    ((float4*)xdbl)[i] = a;
}

// depthwise causal conv (k=4) + bias + SiLU, channel-major, 4 outputs/thread.
__global__ __launch_bounds__(256) void conv_silu(const float* __restrict__ xzT,
        const float* __restrict__ cw, const float* __restrict__ cb,
        float* __restrict__ uT)
{
    int i = blockIdx.x * 256 + threadIdx.x;     // over DI*BL/4
    int d  = i >> 10;
    int q  = i & 1023;
    int bl = q * 4;
    int l  = bl & (L_ - 1);
    const float* row = xzT + (size_t)d * BL;
    float4 cur = *(const float4*)&row[bl];
    float4 prev = make_float4(0.f, 0.f, 0.f, 0.f);
    if (l != 0) prev = *(const float4*)&row[bl - 4];
    float v[7] = { prev.y, prev.z, prev.w, cur.x, cur.y, cur.z, cur.w };
    float w0 = cw[d * 4 + 0], w1 = cw[d * 4 + 1], w2 = cw[d * 4 + 2], w3 = cw[d * 4 + 3];
    float bias = cb[d];
    float4 o;
    o.x = bias + w0 * v[0] + w1 * v[1] + w2 * v[2] + w3 * v[3];
    o.y = bias + w0 * v[1] + w1 * v[2] + w2 * v[3] + w3 * v[4];
    o.z = bias + w0 * v[2] + w1 * v[3] + w2 * v[4] + w3 * v[5];
    o.w = bias + w0 * v[3] + w1 * v[4] + w2 * v[5] + w3 * v[6];
    o.x = o.x / (1.f + __expf(-o.x));
    o.y = o.y / (1.f + __expf(-o.y));
    o.z = o.z / (1.f + __expf(-o.z));
    o.w = o.w / (1.f + __expf(-o.w));
    *(float4*)&uT[(size_t)d * BL + bl] = o;
}

// ---- chunk-decomposed selective scan (G_=16) ----
// thread mapping (pass 1/3): t = [b:2][d:10][seg:4][n:4]
__global__ __launch_bounds__(256) void scan_part1(const float* __restrict__ deltaT,
        const float* __restrict__ uT, const float* __restrict__ xdbl,
        const float* __restrict__ A_log, float* __restrict__ h_end,
        float* __restrict__ Sdv)
{
    const int t = blockIdx.x * 256 + threadIdx.x;
    const int n = t & 15;
    const int seg = (t >> 4) & (G_ - 1);
    const int d = (t >> 8) & (DI - 1);
    const int b = t >> 18;

    const float Acoef = -__expf(A_log[d * NS + n]);
    float h = 0.f, sdv = 0.f;

    const size_t base_t = (size_t)d * BL + b * L_ + seg * SEG;
    const size_t base_x = (size_t)b * L_ * XDC + (size_t)seg * SEG * XDC;

    for (int l0 = 0; l0 < SEG; l0 += 16) {
        float dv[16], uv[16], Bv[16];
        {
            const float4* dp = (const float4*)(deltaT + base_t + l0);
            const float4* up = (const float4*)(uT + base_t + l0);
            #pragma unroll
            for (int i = 0; i < 4; i++) {
                *(float4*)&dv[i * 4] = dp[i];
                *(float4*)&uv[i * 4] = up[i];
            }
        }
        {
            const float* xp = xdbl + base_x + (size_t)l0 * XDC + 32 + n;
            #pragma unroll
            for (int j = 0; j < 16; j++) Bv[j] = xp[j * XDC];
        }
        #pragma unroll
        for (int j = 0; j < 16; j++) {
            sdv += dv[j];
            Bv[j] *= dv[j] * uv[j];
            dv[j] = __expf(dv[j] * Acoef);
        }
        #pragma unroll
        for (int j = 0; j < 16; j++)
            h = fmaf(dv[j], h, Bv[j]);
    }
    const int si = ((b * DI + d) * G_ + seg);
    h_end[si * NS + n] = h;
    if (n == 0) Sdv[si] = sdv;
}

// Pass 2: serial combine across segments -> per-segment initial state h0.
__global__ __launch_bounds__(256) void scan_part2(const float* __restrict__ h_end,
        const float* __restrict__ Sdv, const float* __restrict__ A_log,
        float* __restrict__ h0)
{
    const int t = blockIdx.x * 256 + threadIdx.x;   // B_*DI*NS
    const int n = t & 15;
    const int g = t >> 4;                            // b*DI + d
    const int d = g & (DI - 1);
    const float Acoef = -__expf(A_log[d * NS + n]);
    float H = 0.f;
    #pragma unroll
    for (int s = 0; s < G_; s++) {
        const int si = g * G_ + s;
        h0[si * NS + n] = H;
        H = h_end[si * NS + n] + __expf(Acoef * Sdv[si]) * H;
    }
}

// Pass 3: scan per segment from h0. Halving butterfly: lane n ends with the
// full 16-lane sum for timestep l0+n -> parallel gate, coalesced dword store.
__global__ __launch_bounds__(256) void scan_part3(const float* __restrict__ deltaT,
        const float* __restrict__ uT, const float* __restrict__ xdbl,
        const float* __restrict__ xzT, const float* __restrict__ A_log,
        const float* __restrict__ Dp, const float* __restrict__ h0,
        float* __restrict__ yT)
{
    const int t = blockIdx.x * 256 + threadIdx.x;
    const int n = t & 15;
    const int seg = (t >> 4) & (G_ - 1);
    const int d = (t >> 8) & (DI - 1);
    const int b = t >> 18;

    const float Acoef = -__expf(A_log[d * NS + n]);
    const float Dd = Dp[d];
    float h = h0[((b * DI + d) * G_ + seg) * NS + n];

    const size_t base_t = (size_t)d * BL + b * L_ + seg * SEG;
    const size_t base_z = (size_t)(DI + d) * BL + b * L_ + seg * SEG;
    const size_t base_x = (size_t)b * L_ * XDC + (size_t)seg * SEG * XDC;

    for (int l0 = 0; l0 < SEG; l0 += 16) {
        float ug = uT [base_t + l0 + n];
        float zg = xzT[base_z + l0 + n];

        float dv[16], uv[16];
        {
            const float4* dp = (const float4*)(deltaT + base_t + l0);
            const float4* up = (const float4*)(uT + base_t + l0);
            #pragma unroll
            for (int i = 0; i < 4; i++) {
                *(float4*)&dv[i * 4] = dp[i];
                *(float4*)&uv[i * 4] = up[i];
            }
        }
        float Bv[16], Cv[16];
        {
            const float* xp = xdbl + base_x + (size_t)l0 * XDC + 32 + n;
            #pragma unroll
            for (int j = 0; j < 16; j++) {
                Bv[j] = xp[j * XDC];
                Cv[j] = xp[j * XDC + 16];
            }
        }
        #pragma unroll
        for (int j = 0; j < 16; j++) {
            Bv[j] *= dv[j] * uv[j];
            dv[j] = __expf(dv[j] * Acoef);
        }
        float p[16];
        #pragma unroll
        for (int j = 0; j < 16; j++) {
            h = fmaf(dv[j], h, Bv[j]);
            p[j] = h * Cv[j];
        }

        // halving butterfly: final owner of timestep j is lane n=j.
        float q8[8];
        #pragma unroll
        for (int k = 0; k < 8; k++) {
            float tt = (n & 8) ? p[k] : p[k + 8];
            float rr = __shfl_xor(tt, 8);
            q8[k] = ((n & 8) ? p[k + 8] : p[k]) + rr;
        }
        float q4[4];
        #pragma unroll
        for (int k = 0; k < 4; k++) {
            float tt = (n & 4) ? q8[k] : q8[k + 4];
            float rr = __shfl_xor(tt, 4);
            q4[k] = ((n & 4) ? q8[k + 4] : q8[k]) + rr;
        }
        float q2[2];
        #pragma unroll
        for (int k = 0; k < 2; k++) {
            float tt = (n & 2) ? q4[k] : q4[k + 2];
            float rr = __shfl_xor(tt, 2);
            q2[k] = ((n & 2) ? q4[k + 2] : q4[k]) + rr;
        }
        float tt = (n & 1) ? q2[0] : q2[1];
        float rr = __shfl_xor(tt, 1);
        float S = ((n & 1) ? q2[1] : q2[0]) + rr;

        float v = S + ug * Dd;
        v *= zg / (1.f + __expf(-zg));
        yT[base_t + l0 + n] = v;
    }
}

// yT fp32 [DI][BL] -> yB bf16 [BL][DI], 64x64 LDS tiles.
__global__ __launch_bounds__(256) void transpose_cast(const float* __restrict__ yT,
        ushort* __restrict__ yB)
{
    __shared__ float t[64][65];
    const int bl0 = blockIdx.x * 64, d0 = blockIdx.y * 64;
    const int tid = threadIdx.x;
    #pragma unroll
    for (int i = 0; i < 4; i++) {
        int chunk = tid + i * 256;
        int dr = chunk >> 4, c4 = (chunk & 15) * 4;
        const float4 v = *(const float4*)&yT[(size_t)(d0 + dr) * BL + bl0 + c4];
        t[dr][c4 + 0] = v.x; t[dr][c4 + 1] = v.y;
        t[dr][c4 + 2] = v.z; t[dr][c4 + 3] = v.w;
    }
    __syncthreads();
    #pragma unroll
    for (int i = 0; i < 4; i++) {
        int chunk = tid + i * 256;
        int br = chunk >> 4, dc4 = (chunk & 15) * 4;
        ushort4 o;
        o.x = f2bf(t[dc4 + 0][br]); o.y = f2bf(t[dc4 + 1][br]);
        o.z = f2bf(t[dc4 + 2][br]); o.w = f2bf(t[dc4 + 3][br]);
        *(ushort4*)&yB[(size_t)(bl0 + br) * DI + d0 + dc4] = o;
    }
}

// LayerNorm over last dim (512), one block per row, fp32 out.
__global__ __launch_bounds__(256) void ln_kernel(const float* __restrict__ r,
        const float* __restrict__ lnw, const float* __restrict__ lnb,
        float* __restrict__ out)
{
    int row = blockIdx.x;
    const float* rr = r + (size_t)row * DM;
    float v0 = rr[threadIdx.x], v1 = rr[threadIdx.x + 256];
    float s = v0 + v1, s2 = v0 * v0 + v1 * v1;
    #pragma unroll
    for (int off = 32; off > 0; off >>= 1) {
        s  += __shfl_down(s, off);
        s2 += __shfl_down(s2, off);
    }
    __shared__ float ls[4], ls2[4];
    __shared__ float mu_s, rstd_s;
    int wid = threadIdx.x >> 6, lane = threadIdx.x & 63;
    if (lane == 0) { ls[wid] = s; ls2[wid] = s2; }
    __syncthreads();
    if (threadIdx.x == 0) {
        float S = ls[0] + ls[1] + ls[2] + ls[3];
        float S2 = ls2[0] + ls2[1] + ls2[2] + ls2[3];
        float mu = S * (1.f / DM);
        float var = S2 * (1.f / DM) - mu * mu;
        mu_s = mu;
        rstd_s = rsqrtf(var + 1e-5f);
    }
    __syncthreads();
    float mu = mu_s, rstd = rstd_s;
    out[(size_t)row * DM + threadIdx.x] =
        (v0 - mu) * rstd * lnw[threadIdx.x] + lnb[threadIdx.x];
    out[(size_t)row * DM + threadIdx.x + 256] =
        (v1 - mu) * rstd * lnw[threadIdx.x + 256] + lnb[threadIdx.x + 256];
}

extern "C" void kernel_launch(void* const* d_in, const int* in_sizes, int n_in,
                              void* d_out, int out_size, void* d_ws, size_t ws_size,
                              hipStream_t stream)
{
    const float* x         = (const float*)d_in[0];
    const float* in_proj_w = (const float*)d_in[1];
    const float* conv_w    = (const float*)d_in[2];
    const float* conv_b    = (const float*)d_in[3];
    const float* x_proj_w  = (const float*)d_in[4];
    const float* dt_proj_w = (const float*)d_in[5];
    const float* dt_proj_b = (const float*)d_in[6];
    const float* A_log     = (const float*)d_in[7];
    const float* Dvec      = (const float*)d_in[8];
    const float* out_proj_w= (const float*)d_in[9];
    const float* ln_w      = (const float*)d_in[10];
    const float* ln_b      = (const float*)d_in[11];
    float* out = (float*)d_out;

    // fp32 regions (floats)
    float* ws     = (float*)d_ws;
    float* xzT    = ws;                                  // 2048 x 4096 (32 MB)
    float* uT     = xzT    + (size_t)2048 * BL;          // 1024 x 4096 (16 MB)
    float* xdbl   = uT     + (size_t)DI * BL;            // 4096 x 64   (1 MB)
    float* deltaT = xdbl   + (size_t)BL * XDC;           // 1024 x 4096 (16 MB)
    float* yT     = deltaT + (size_t)DI * BL;            // 1024 x 4096 (16 MB)
    float* r      = yT     + (size_t)DI * BL;            // 4096 x 512  (8 MB)
    // aliases over time-dead regions (sequential reuse, no overlap in time):
    ushort* xB    = (ushort*)yT;                          // 4 MB, dead after gemm1
    float*  xdblp = yT;                                   // KS*BL*XDC fl = 4 MB, gemm3 partials (after gemm1)
    float*  Sdv   = yT + (size_t)KS * BL * XDC;           // 0.26 MB, dead before part3 writes yT
    ushort* yB    = (ushort*)deltaT;                      // deltaT dead after scan part3
    ushort* wOutB = (ushort*)deltaT + (size_t)4 * 1024 * 1024;
    ushort* wInB  = (ushort*)deltaT + (size_t)9 * 1024 * 1024 / 2;
    // scan summaries fill r exactly (dead until gemm6b): 2 x 4 MB
    float* h_end  = r;                                   // B*DI*G*NS = 1048576 floats
    float* h0     = r + (size_t)B_ * DI * G_ * NS;       // 1048576 floats

    dim3 blk(256);

    // 0) casts for gemm1
    cast_bf16<<<(BL * DM / 4 + 255) / 256, blk, 0, stream>>>(x, xB, BL * DM / 4);
    cast_bf16<<<(2048 * DM / 4 + 255) / 256, blk, 0, stream>>>(in_proj_w, wInB, 2048 * DM / 4);

    // 1) xzT[e][bl] = in_proj_w @ x^T : M=2048, N=4096, K=512 (MFMA)
    gemm_mfma<0><<<dim3(BL / 128, 2048 / 128), blk, 0, stream>>>(
        wInB, xB, xzT, DM, BL, nullptr);

    // 2) uT = silu(causal_conv(xsT) + cb)
    conv_silu<<<(DI * BL / 4) / 256, blk, 0, stream>>>(xzT, conv_w, conv_b, uT);

    // 3) xdbl = u @ x_proj_w^T : split-K partials + reduce
    gemm3_splitk<<<dim3(KS, BL / 32), blk, 0, stream>>>(uT, x_proj_w, xdblp);
    gemm3_reduce<<<(BL * XDC / 4) / 256, blk, 0, stream>>>(xdblp, xdbl);

    // 4) deltaT = softplus(dt_proj_w @ dt^T + b[m]) : M=1024, N=4096, K=32
    gemm_tn128<<<dim3(BL / 64, DI / 128), blk, 0, stream>>>(
        dt_proj_w, xdbl, deltaT, BL, 32, 32, XDC, BL, dt_proj_b);

    // 5) chunk-decomposed selective scan + gate (G=16)
    scan_part1<<<(B_ * DI * G_ * NS) / 256, blk, 0, stream>>>(
        deltaT, uT, xdbl, A_log, h_end, Sdv);
    scan_part2<<<(B_ * DI * NS) / 256, blk, 0, stream>>>(
        h_end, Sdv, A_log, h0);
    scan_part3<<<(B_ * DI * G_ * NS) / 256, blk, 0, stream>>>(
        deltaT, uT, xdbl, xzT, A_log, Dvec, h0, yT);

    // 6a) yT -> yB (bf16, [bl][d]); cast out_proj_w
    transpose_cast<<<dim3(BL / 64, DI / 64), blk, 0, stream>>>(yT, yB);
    cast_bf16<<<(DM * DI / 4 + 255) / 256, blk, 0, stream>>>(out_proj_w, wOutB, DM * DI / 4);

    // 6b) r[bl][dm] = y @ out_proj_w^T + x : M=4096, N=512, K=1024 (MFMA, resid epi)
    gemm_mfma<2><<<dim3(DM / 128, BL / 128), blk, 0, stream>>>(
        yB, wOutB, r, DI, DM, x);

    // 7) LayerNorm -> fp32 out
    ln_kernel<<<BL, blk, 0, stream>>>(r, ln_w, ln_b, out);
}

// Round 10
// 269.492 us; speedup vs baseline: 2.1910x; 1.0059x over previous
//
#include <hip/hip_runtime.h>
#include <hip/hip_bf16.h>
#include <math.h>

// MambaBlock: B=4, L=1024, D_MODEL=512, D_INNER=1024, D_STATE=16, D_CONV=4, DT_RANK=32
// fp32 in/out. bf16 MFMA for gemm1/gemm4/gemm6; fp32 SIMT split-K for gemm3.
// Scan: single fused kernel (block = one (b,d); 16 segs x 16 n = 256 threads;
// LDS-resident segment summaries; halving butterfly in phase C).
#define B_   4
#define L_   1024
#define DM   512
#define DI   1024
#define NS   16
#define XDC  64      // DT_RANK + 2*D_STATE
#define BL   4096    // B_*L_
#define G_   16      // scan segments
#define SEG  64      // L_/G_
#define KS   4       // gemm3 split-K factor

typedef short bfrag __attribute__((ext_vector_type(8)));   // 8 bf16
typedef float ffrag __attribute__((ext_vector_type(4)));   // 4 fp32 acc

__device__ __forceinline__ ushort f2bf(float v) {
    __hip_bfloat16 h = __float2bfloat16(v);
    return *(ushort*)&h;
}

// fp32 -> bf16 cast, 4 elems/thread
__global__ __launch_bounds__(256) void cast_bf16(const float* __restrict__ in,
        ushort* __restrict__ out, int n4)
{
    int i = blockIdx.x * 256 + threadIdx.x;
    if (i >= n4) return;
    float4 v = ((const float4*)in)[i];
    ushort4 o;
    o.x = f2bf(v.x); o.y = f2bf(v.y); o.z = f2bf(v.z); o.w = f2bf(v.w);
    ((ushort4*)out)[i] = o;
}

// MFMA bf16 TN GEMM: C[M,N] = A[M,K] * B[N,K]^T, fp32 out.
// 128x128 block tile, BK=32, 4 waves (2x2), wave tile 64x64 (4x4 of 16x16x32).
// EPI: 0 none; 2 C += resid[m*ldc+n]; 3 softplus(C + bias[m])
template<int EPI>
__global__ __launch_bounds__(256) void gemm_mfma(const ushort* __restrict__ A,
        const ushort* __restrict__ B, float* __restrict__ C,
        int K, int ldc, const float* __restrict__ resid,
        const float* __restrict__ bias)
{
    __shared__ ushort As[128][40];
    __shared__ ushort Bs[128][40];
    const int tid = threadIdx.x;
    const int lane = tid & 63, wave = tid >> 6;
    const int wm = (wave & 1) * 64, wn = (wave >> 1) * 64;
    const int l15 = lane & 15, quad = lane >> 4;
    const int m0 = blockIdx.y * 128, n0 = blockIdx.x * 128;

    ffrag acc[4][4] = {};

    for (int k0 = 0; k0 < K; k0 += 32) {
        #pragma unroll
        for (int i = 0; i < 2; i++) {
            int chunk = tid + i * 256;
            int row = chunk >> 2, kk8 = (chunk & 3) * 8;
            *(uint4*)&As[row][kk8] = *(const uint4*)&A[(size_t)(m0 + row) * K + k0 + kk8];
            *(uint4*)&Bs[row][kk8] = *(const uint4*)&B[(size_t)(n0 + row) * K + k0 + kk8];
        }
        __syncthreads();
        bfrag af[4], bfv[4];
        #pragma unroll
        for (int i = 0; i < 4; i++) {
            af[i]  = *(const bfrag*)&As[wm + i * 16 + l15][quad * 8];
            bfv[i] = *(const bfrag*)&Bs[wn + i * 16 + l15][quad * 8];
        }
        #pragma unroll
        for (int i = 0; i < 4; i++)
            #pragma unroll
            for (int j = 0; j < 4; j++)
                acc[i][j] = __builtin_amdgcn_mfma_f32_16x16x32_bf16(af[i], bfv[j], acc[i][j], 0, 0, 0);
        __syncthreads();
    }

    #pragma unroll
    for (int i = 0; i < 4; i++) {
        #pragma unroll
        for (int j = 0; j < 4; j++) {
            int n = n0 + wn + j * 16 + l15;
            #pragma unroll
            for (int r = 0; r < 4; r++) {
                int m = m0 + wm + i * 16 + quad * 4 + r;
                float v = acc[i][j][r];
                if (EPI == 2) v += resid[(size_t)m * ldc + n];
                if (EPI == 3) {
                    v += bias[m];
                    v = (v > 20.f) ? v : log1pf(__expf(v));
                }
                C[(size_t)m * ldc + n] = v;
            }
        }
    }
}

// gemm3 split-K: part[ks][m][n] = sum over K-chunk ks of u[m][k]*W[n][k].
// A = uT [K=DI][M=BL] (transposed), W = x_proj_w [64][DI].
// Block: 32 m-rows x 64 n-cols, K-chunk = DI/KS = 256, BK=16.
__global__ __launch_bounds__(256) void gemm3_splitk(const float* __restrict__ uT,
        const float* __restrict__ xw, float* __restrict__ part)
{
    __shared__ float As[16][33];    // [k][m] 32 m
    __shared__ float Ws[16][68];    // [k][n] 64 n
    const int tid = threadIdx.x;
    const int tx = tid & 15, ty = tid >> 4;
    const int ks = blockIdx.x, m0 = blockIdx.y * 32;
    const int kbase = ks * (DI / KS);
    float acc[2][4] = {};

    for (int k0 = 0; k0 < DI / KS; k0 += 16) {
        if (tid < 128) {
            int k = tid >> 3, m4 = (tid & 7) * 4;
            const float4 v = *(const float4*)&uT[(size_t)(kbase + k0 + k) * BL + m0 + m4];
            As[k][m4 + 0] = v.x; As[k][m4 + 1] = v.y;
            As[k][m4 + 2] = v.z; As[k][m4 + 3] = v.w;
        }
        {
            int r = tid >> 2, c4 = (tid & 3) * 4;
            const float4 v = *(const float4*)&xw[(size_t)r * DI + kbase + k0 + c4];
            Ws[c4 + 0][r] = v.x; Ws[c4 + 1][r] = v.y;
            Ws[c4 + 2][r] = v.z; Ws[c4 + 3][r] = v.w;
        }
        __syncthreads();
        #pragma unroll
        for (int kk = 0; kk < 16; kk++) {
            float a[2], b[4];
            a[0] = As[kk][ty * 2 + 0];
            a[1] = As[kk][ty * 2 + 1];
            #pragma unroll
            for (int j = 0; j < 4; j++) b[j] = Ws[kk][tx * 4 + j];
            #pragma unroll
            for (int i = 0; i < 2; i++)
                #pragma unroll
                for (int j = 0; j < 4; j++)
                    acc[i][j] = fmaf(a[i], b[j], acc[i][j]);
        }
        __syncthreads();
    }

    float* pp = part + (size_t)ks * BL * XDC;
    #pragma unroll
    for (int i = 0; i < 2; i++) {
        int m = m0 + ty * 2 + i;
        *(float4*)&pp[(size_t)m * XDC + tx * 4] =
            make_float4(acc[i][0], acc[i][1], acc[i][2], acc[i][3]);
    }
}

// reduce KS partials -> xdbl; also emit bf16 copy of dt columns (0..31) for gemm4.
__global__ __launch_bounds__(256) void gemm3_reduce(const float* __restrict__ part,
        float* __restrict__ xdbl, ushort* __restrict__ dtB)
{
    int i = blockIdx.x * 256 + threadIdx.x;     // over BL*XDC/4
    const float4* p0 = (const float4*)part;
    float4 a = p0[i];
    #pragma unroll
    for (int s = 1; s < KS; s++) {
        float4 b = p0[i + (size_t)s * BL * XDC / 4];
        a.x += b.x; a.y += b.y; a.z += b.z; a.w += b.w;
    }
    ((float4*)xdbl)[i] = a;
    int c4 = i & 15;                // float4 index within the 64-wide row
    if (c4 < 8) {                   // dt columns 0..31
        int m = i >> 4;
        ushort4 o;
        o.x = f2bf(a.x); o.y = f2bf(a.y); o.z = f2bf(a.z); o.w = f2bf(a.w);
        ((ushort4*)dtB)[m * 8 + c4] = o;
    }
}

// depthwise causal conv (k=4) + bias + SiLU, channel-major, 4 outputs/thread.
__global__ __launch_bounds__(256) void conv_silu(const float* __restrict__ xzT,
        const float* __restrict__ cw, const float* __restrict__ cb,
        float* __restrict__ uT)
{
    int i = blockIdx.x * 256 + threadIdx.x;     // over DI*BL/4
    int d  = i >> 10;
    int q  = i & 1023;
    int bl = q * 4;
    int l  = bl & (L_ - 1);
    const float* row = xzT + (size_t)d * BL;
    float4 cur = *(const float4*)&row[bl];
    float4 prev = make_float4(0.f, 0.f, 0.f, 0.f);
    if (l != 0) prev = *(const float4*)&row[bl - 4];
    float v[7] = { prev.y, prev.z, prev.w, cur.x, cur.y, cur.z, cur.w };
    float w0 = cw[d * 4 + 0], w1 = cw[d * 4 + 1], w2 = cw[d * 4 + 2], w3 = cw[d * 4 + 3];
    float bias = cb[d];
    float4 o;
    o.x = bias + w0 * v[0] + w1 * v[1] + w2 * v[2] + w3 * v[3];
    o.y = bias + w0 * v[1] + w1 * v[2] + w2 * v[3] + w3 * v[4];
    o.z = bias + w0 * v[2] + w1 * v[3] + w2 * v[4] + w3 * v[5];
    o.w = bias + w0 * v[3] + w1 * v[4] + w2 * v[5] + w3 * v[6];
    o.x = o.x / (1.f + __expf(-o.x));
    o.y = o.y / (1.f + __expf(-o.y));
    o.z = o.z / (1.f + __expf(-o.z));
    o.w = o.w / (1.f + __expf(-o.w));
    *(float4*)&uT[(size_t)d * BL + bl] = o;
}

// ---- fused chunk-decomposed selective scan ----
// One block per (b,d): 16 segments x 16 n-lanes = 256 threads.
// Phase A: local scan (h0=0) -> h_end, sum(delta) in LDS.
// Phase B: 16 threads serially combine the 16 segments -> h0 in LDS.
// Phase C: re-scan from h0 with halving butterfly; lane n owns timestep l0+n
// -> parallel gate, coalesced store.
__global__ __launch_bounds__(256) void scan_fused(const float* __restrict__ deltaT,
        const float* __restrict__ uT, const float* __restrict__ xdbl,
        const float* __restrict__ xzT, const float* __restrict__ A_log,
        const float* __restrict__ Dp, float* __restrict__ yT)
{
    __shared__ float hend_s[G_][NS + 1];
    __shared__ float h0_s[G_][NS + 1];
    __shared__ float sdv_s[G_];

    const int tid = threadIdx.x;
    const int n = tid & 15;
    const int seg = tid >> 4;          // 0..15
    const int bd = blockIdx.x;         // b*DI + d
    const int d = bd & (DI - 1);
    const int b = bd >> 10;

    const float Acoef = -__expf(A_log[d * NS + n]);
    const float Dd = Dp[d];

    const size_t base_t = (size_t)d * BL + b * L_ + seg * SEG;
    const size_t base_z = (size_t)(DI + d) * BL + b * L_ + seg * SEG;
    const size_t base_x = (size_t)b * L_ * XDC + (size_t)seg * SEG * XDC;

    // ---- Phase A ----
    float h = 0.f, sdv = 0.f;
    for (int l0 = 0; l0 < SEG; l0 += 16) {
        float dv[16], uv[16], Bv[16];
        {
            const float4* dp = (const float4*)(deltaT + base_t + l0);
            const float4* up = (const float4*)(uT + base_t + l0);
            #pragma unroll
            for (int i = 0; i < 4; i++) {
                *(float4*)&dv[i * 4] = dp[i];
                *(float4*)&uv[i * 4] = up[i];
            }
        }
        {
            const float* xp = xdbl + base_x + (size_t)l0 * XDC + 32 + n;
            #pragma unroll
            for (int j = 0; j < 16; j++) Bv[j] = xp[j * XDC];
        }
        #pragma unroll
        for (int j = 0; j < 16; j++) {
            sdv += dv[j];
            Bv[j] *= dv[j] * uv[j];
            dv[j] = __expf(dv[j] * Acoef);
        }
        #pragma unroll
        for (int j = 0; j < 16; j++)
            h = fmaf(dv[j], h, Bv[j]);
    }
    hend_s[seg][n] = h;
    if (n == 0) sdv_s[seg] = sdv;
    __syncthreads();

    // ---- Phase B ----
    if (seg == 0) {
        float H = 0.f;
        #pragma unroll
        for (int s = 0; s < G_; s++) {
            h0_s[s][n] = H;
            H = hend_s[s][n] + __expf(Acoef * sdv_s[s]) * H;
        }
    }
    __syncthreads();

    // ---- Phase C ----
    h = h0_s[seg][n];
    for (int l0 = 0; l0 < SEG; l0 += 16) {
        float ug = uT [base_t + l0 + n];
        float zg = xzT[base_z + l0 + n];

        float dv[16], uv[16];
        {
            const float4* dp = (const float4*)(deltaT + base_t + l0);
            const float4* up = (const float4*)(uT + base_t + l0);
            #pragma unroll
            for (int i = 0; i < 4; i++) {
                *(float4*)&dv[i * 4] = dp[i];
                *(float4*)&uv[i * 4] = up[i];
            }
        }
        float Bv[16], Cv[16];
        {
            const float* xp = xdbl + base_x + (size_t)l0 * XDC + 32 + n;
            #pragma unroll
            for (int j = 0; j < 16; j++) {
                Bv[j] = xp[j * XDC];
                Cv[j] = xp[j * XDC + 16];
            }
        }
        #pragma unroll
        for (int j = 0; j < 16; j++) {
            Bv[j] *= dv[j] * uv[j];
            dv[j] = __expf(dv[j] * Acoef);
        }
        float p[16];
        #pragma unroll
        for (int j = 0; j < 16; j++) {
            h = fmaf(dv[j], h, Bv[j]);
            p[j] = h * Cv[j];
        }

        // halving butterfly: final owner of timestep j is lane n=j.
        float q8[8];
        #pragma unroll
        for (int k = 0; k < 8; k++) {
            float tt = (n & 8) ? p[k] : p[k + 8];
            float rr = __shfl_xor(tt, 8);
            q8[k] = ((n & 8) ? p[k + 8] : p[k]) + rr;
        }
        float q4[4];
        #pragma unroll
        for (int k = 0; k < 4; k++) {
            float tt = (n & 4) ? q8[k] : q8[k + 4];
            float rr = __shfl_xor(tt, 4);
            q4[k] = ((n & 4) ? q8[k + 4] : q8[k]) + rr;
        }
        float q2[2];
        #pragma unroll
        for (int k = 0; k < 2; k++) {
            float tt = (n & 2) ? q4[k] : q4[k + 2];
            float rr = __shfl_xor(tt, 2);
            q2[k] = ((n & 2) ? q4[k + 2] : q4[k]) + rr;
        }
        float tt = (n & 1) ? q2[0] : q2[1];
        float rr = __shfl_xor(tt, 1);
        float S = ((n & 1) ? q2[1] : q2[0]) + rr;

        float v = S + ug * Dd;
        v *= zg / (1.f + __expf(-zg));
        yT[base_t + l0 + n] = v;
    }
}

// yT fp32 [DI][BL] -> yB bf16 [BL][DI], 64x64 LDS tiles.
__global__ __launch_bounds__(256) void transpose_cast(const float* __restrict__ yT,
        ushort* __restrict__ yB)
{
    __shared__ float t[64][65];
    const int bl0 = blockIdx.x * 64, d0 = blockIdx.y * 64;
    const int tid = threadIdx.x;
    #pragma unroll
    for (int i = 0; i < 4; i++) {
        int chunk = tid + i * 256;
        int dr = chunk >> 4, c4 = (chunk & 15) * 4;
        const float4 v = *(const float4*)&yT[(size_t)(d0 + dr) * BL + bl0 + c4];
        t[dr][c4 + 0] = v.x; t[dr][c4 + 1] = v.y;
        t[dr][c4 + 2] = v.z; t[dr][c4 + 3] = v.w;
    }
    __syncthreads();
    #pragma unroll
    for (int i = 0; i < 4; i++) {
        int chunk = tid + i * 256;
        int br = chunk >> 4, dc4 = (chunk & 15) * 4;
        ushort4 o;
        o.x = f2bf(t[dc4 + 0][br]); o.y = f2bf(t[dc4 + 1][br]);
        o.z = f2bf(t[dc4 + 2][br]); o.w = f2bf(t[dc4 + 3][br]);
        *(ushort4*)&yB[(size_t)(bl0 + br) * DI + d0 + dc4] = o;
    }
}

// LayerNorm over last dim (512), one block per row, fp32 out.
__global__ __launch_bounds__(256) void ln_kernel(const float* __restrict__ r,
        const float* __restrict__ lnw, const float* __restrict__ lnb,
        float* __restrict__ out)
{
    int row = blockIdx.x;
    const float* rr = r + (size_t)row * DM;
    float v0 = rr[threadIdx.x], v1 = rr[threadIdx.x + 256];
    float s = v0 + v1, s2 = v0 * v0 + v1 * v1;
    #pragma unroll
    for (int off = 32; off > 0; off >>= 1) {
        s  += __shfl_down(s, off);
        s2 += __shfl_down(s2, off);
    }
    __shared__ float ls[4], ls2[4];
    __shared__ float mu_s, rstd_s;
    int wid = threadIdx.x >> 6, lane = threadIdx.x & 63;
    if (lane == 0) { ls[wid] = s; ls2[wid] = s2; }
    __syncthreads();
    if (threadIdx.x == 0) {
        float S = ls[0] + ls[1] + ls[2] + ls[3];
        float S2 = ls2[0] + ls2[1] + ls2[2] + ls2[3];
        float mu = S * (1.f / DM);
        float var = S2 * (1.f / DM) - mu * mu;
        mu_s = mu;
        rstd_s = rsqrtf(var + 1e-5f);
    }
    __syncthreads();
    float mu = mu_s, rstd = rstd_s;
    out[(size_t)row * DM + threadIdx.x] =
        (v0 - mu) * rstd * lnw[threadIdx.x] + lnb[threadIdx.x];
    out[(size_t)row * DM + threadIdx.x + 256] =
        (v1 - mu) * rstd * lnw[threadIdx.x + 256] + lnb[threadIdx.x + 256];
}

extern "C" void kernel_launch(void* const* d_in, const int* in_sizes, int n_in,
                              void* d_out, int out_size, void* d_ws, size_t ws_size,
                              hipStream_t stream)
{
    const float* x         = (const float*)d_in[0];
    const float* in_proj_w = (const float*)d_in[1];
    const float* conv_w    = (const float*)d_in[2];
    const float* conv_b    = (const float*)d_in[3];
    const float* x_proj_w  = (const float*)d_in[4];
    const float* dt_proj_w = (const float*)d_in[5];
    const float* dt_proj_b = (const float*)d_in[6];
    const float* A_log     = (const float*)d_in[7];
    const float* Dvec      = (const float*)d_in[8];
    const float* out_proj_w= (const float*)d_in[9];
    const float* ln_w      = (const float*)d_in[10];
    const float* ln_b      = (const float*)d_in[11];
    float* out = (float*)d_out;

    // fp32 regions (floats)
    float* ws     = (float*)d_ws;
    float* xzT    = ws;                                  // 2048 x 4096 (32 MB)
    float* uT     = xzT    + (size_t)2048 * BL;          // 1024 x 4096 (16 MB)
    float* xdbl   = uT     + (size_t)DI * BL;            // 4096 x 64   (1 MB)
    float* deltaT = xdbl   + (size_t)BL * XDC;           // 1024 x 4096 (16 MB)
    float* yT     = deltaT + (size_t)DI * BL;            // 1024 x 4096 (16 MB)
    float* r      = yT     + (size_t)DI * BL;            // 4096 x 512  (8 MB)
    // aliases over time-dead regions (sequential reuse, no overlap in time):
    ushort* xB    = (ushort*)yT;                          // 4 MB, dead after gemm1
    float*  xdblp = yT;                                   // KS*BL*XDC fl = 4 MB, gemm3 partials
    ushort* yB    = (ushort*)deltaT;                      // deltaT dead after scan
    ushort* wOutB = (ushort*)deltaT + (size_t)4 * 1024 * 1024;   // byte off 8 MB
    ushort* wInB  = (ushort*)deltaT + (size_t)9 * 1024 * 1024 / 2; // byte off 9 MB
    // r region is free until gemm6b: dt bf16 operands for gemm4 live here
    ushort* dtB   = (ushort*)r;                          // 4096 x 32 bf16 (256 KB)
    ushort* dtwB  = (ushort*)r + (size_t)BL * 32;        // 1024 x 32 bf16 (64 KB)

    dim3 blk(256);

    // 0) casts for gemm1 + dt_proj_w
    cast_bf16<<<(BL * DM / 4 + 255) / 256, blk, 0, stream>>>(x, xB, BL * DM / 4);
    cast_bf16<<<(2048 * DM / 4 + 255) / 256, blk, 0, stream>>>(in_proj_w, wInB, 2048 * DM / 4);
    cast_bf16<<<(DI * 32 / 4 + 255) / 256, blk, 0, stream>>>(dt_proj_w, dtwB, DI * 32 / 4);

    // 1) xzT[e][bl] = in_proj_w @ x^T : M=2048, N=4096, K=512 (MFMA)
    gemm_mfma<0><<<dim3(BL / 128, 2048 / 128), blk, 0, stream>>>(
        wInB, xB, xzT, DM, BL, nullptr, nullptr);

    // 2) uT = silu(causal_conv(xsT) + cb)
    conv_silu<<<(DI * BL / 4) / 256, blk, 0, stream>>>(xzT, conv_w, conv_b, uT);

    // 3) xdbl = u @ x_proj_w^T : split-K partials + reduce (+ dt bf16 emit)
    gemm3_splitk<<<dim3(KS, BL / 32), blk, 0, stream>>>(uT, x_proj_w, xdblp);
    gemm3_reduce<<<(BL * XDC / 4) / 256, blk, 0, stream>>>(xdblp, xdbl, dtB);

    // 4) deltaT[d][bl] = softplus(dt_proj_w @ dt^T + b[d]) : M=1024, N=4096, K=32 (MFMA)
    gemm_mfma<3><<<dim3(BL / 128, DI / 128), blk, 0, stream>>>(
        dtwB, dtB, deltaT, 32, BL, nullptr, dt_proj_b);

    // 5) fused selective scan + gate (one block per (b,d))
    scan_fused<<<B_ * DI, blk, 0, stream>>>(
        deltaT, uT, xdbl, xzT, A_log, Dvec, yT);

    // 6a) yT -> yB (bf16, [bl][d]); cast out_proj_w
    transpose_cast<<<dim3(BL / 64, DI / 64), blk, 0, stream>>>(yT, yB);
    cast_bf16<<<(DM * DI / 4 + 255) / 256, blk, 0, stream>>>(out_proj_w, wOutB, DM * DI / 4);

    // 6b) r[bl][dm] = y @ out_proj_w^T + x : M=4096, N=512, K=1024 (MFMA, resid epi)
    gemm_mfma<2><<<dim3(DM / 128, BL / 128), blk, 0, stream>>>(
        yB, wOutB, r, DI, DM, x, nullptr);

    // 7) LayerNorm -> fp32 out
    ln_kernel<<<BL, blk, 0, stream>>>(r, ln_w, ln_b, out);
}